// Round 2
// baseline (1508.936 us; speedup 1.0000x reference)
//
#include <hip/hip_runtime.h>
#include <hip/hip_bf16.h>

// MORAL: 3x GCNConv on N=100000 nodes, E=1.6M edges. All fp32 I/O.
// deg/dinv shared across convs. Branch1: project(512->64) then aggregate.
// Branch2: aggregate 6-dim gated structure, then W_s. Branch3: project(128->7)
// then aggregate. fp32 accumulators in ws.

__global__ void detect_k(const int* __restrict__ ei32, int* __restrict__ flag, int E) {
    int i = blockIdx.x * 256 + threadIdx.x;
    bool nz = (i < E) && (ei32[2 * i + 1] != 0);
    if (__any(nz) && (threadIdx.x & 63) == 0) atomicOr(flag, 1);
}

__global__ void setup_k(const float* __restrict__ emb,
                        const float* __restrict__ embW,
                        const float* __restrict__ alpha_s,
                        const float* __restrict__ alpha_a,
                        float* __restrict__ cw) {
    int lane = threadIdx.x;  // 64 threads
    float w = embW[lane];
    #pragma unroll
    for (int k = 0; k < 6; k++) {
        float p = emb[k * 64 + lane] * w;
        #pragma unroll
        for (int off = 32; off; off >>= 1) p += __shfl_xor(p, off);
        if (lane == 0) cw[k] = (p < 0.0f) ? 0.0f : 1.0f;  // sigmoid(p)<0.5 <=> p<0
    }
    if (lane == 0) {
        float s = alpha_s[0];
        float a = alpha_a[0];
        float inv = 1.0f / (fabsf(s) + fabsf(a));
        cw[6] = 2.0f * a * inv;  // scale on attr (h_f)
        cw[7] = 2.0f * s * inv;  // scale on struc (h_s)
    }
}

__device__ __forceinline__ void load_edge(const void* ei, int e, int E, int flag,
                                          int& r, int& c) {
    if (flag) {
        const int* p = (const int*)ei;
        r = p[e]; c = p[E + e];
    } else {
        const long long* p = (const long long*)ei;
        r = (int)p[e]; c = (int)p[(size_t)E + e];
    }
}

__global__ void deg_k(const void* __restrict__ ei, const float* __restrict__ cw,
                      unsigned* __restrict__ deg, int E) {
    int e = blockIdx.x * 256 + threadIdx.x;
    if (e >= E) return;
    int flag = ((const int*)cw)[8];
    int c = flag ? ((const int*)ei)[E + e]
                 : (int)((const long long*)ei)[(size_t)E + e];
    atomicAdd(&deg[c], 1u);
}

__global__ void dinv_k(const unsigned* __restrict__ deg, float* __restrict__ dinv, int n) {
    int i = blockIdx.x * 256 + threadIdx.x;
    if (i < n) dinv[i] = rsqrtf((float)deg[i] + 1.0f);  // +1 = self-loop
}

// xf = feature @ W_f  (f32). Wave computes 4 rows x 64 cols.
__global__ __launch_bounds__(256) void gemm_f_k(const float* __restrict__ feat,
                                                const float* __restrict__ Wf,
                                                float* __restrict__ xf, int n) {
    int lane = threadIdx.x & 63;
    int wid = threadIdx.x >> 6;
    int row0 = (blockIdx.x * 4 + wid) * 4;
    if (row0 >= n) return;
    const float* f0 = feat + (size_t)row0 * 512;
    float acc0 = 0, acc1 = 0, acc2 = 0, acc3 = 0;
    for (int k0 = 0; k0 < 512; k0 += 64) {
        float fv0 = f0[k0 + lane];
        float fv1 = f0[512 + k0 + lane];
        float fv2 = f0[1024 + k0 + lane];
        float fv3 = f0[1536 + k0 + lane];
        #pragma unroll
        for (int j = 0; j < 64; j++) {
            float w = Wf[(k0 + j) * 64 + lane];
            acc0 += __shfl(fv0, j) * w;
            acc1 += __shfl(fv1, j) * w;
            acc2 += __shfl(fv2, j) * w;
            acc3 += __shfl(fv3, j) * w;
        }
    }
    size_t o = (size_t)row0 * 64 + lane;
    xf[o] = acc0; xf[o + 64] = acc1; xf[o + 128] = acc2; xf[o + 192] = acc3;
}

// Self-loop init: af[i] = xf[i]*dinv[i]^2 ; as6[i][k] = structure[i][k]*gate[k]*dinv^2
__global__ __launch_bounds__(256) void init_fs_k(const float* __restrict__ xf,
                                                 const float* __restrict__ structure,
                                                 const float* __restrict__ dinv,
                                                 const float* __restrict__ cw,
                                                 float* __restrict__ af,
                                                 float* __restrict__ as6, int n) {
    int i = blockIdx.x * 4 + (threadIdx.x >> 6);
    int lane = threadIdx.x & 63;
    if (i >= n) return;
    float d = dinv[i];
    float d2 = d * d;
    af[(size_t)i * 64 + lane] = xf[(size_t)i * 64 + lane] * d2;
    if (lane < 6)
        as6[i * 6 + lane] = structure[i * 6 + lane] * cw[lane] * d2;
}

// Edge scatter for branches 1 & 2: one wave per edge.
__global__ __launch_bounds__(256) void scatter_fs_k(const void* __restrict__ ei,
                                                    const float* __restrict__ xf,
                                                    const float* __restrict__ structure,
                                                    const float* __restrict__ dinv,
                                                    const float* __restrict__ cw,
                                                    float* __restrict__ af,
                                                    float* __restrict__ as6, int E) {
    int e = blockIdx.x * 4 + (threadIdx.x >> 6);
    int lane = threadIdx.x & 63;
    if (e >= E) return;
    int flag = ((const int*)cw)[8];
    int r, c;
    load_edge(ei, e, E, flag, r, c);
    float nrm = dinv[r] * dinv[c];
    atomicAdd(&af[(size_t)c * 64 + lane], xf[(size_t)r * 64 + lane] * nrm);
    if (lane < 6)
        atomicAdd(&as6[c * 6 + lane], structure[r * 6 + lane] * cw[lane] * nrm);
}

// Finalize h_f, h_s and project to xr = x @ W_r (7), init ay self-loop.
__global__ __launch_bounds__(256) void finalize1_k(const float* __restrict__ af,
                                                   const float* __restrict__ as6,
                                                   const float* __restrict__ bf,
                                                   const float* __restrict__ Ws,
                                                   const float* __restrict__ bs,
                                                   const float* __restrict__ Wr,
                                                   const float* __restrict__ dinv,
                                                   const float* __restrict__ cw,
                                                   float* __restrict__ out_hf,
                                                   float* __restrict__ out_hs,
                                                   float* __restrict__ xr,
                                                   float* __restrict__ ay, int n) {
    int i = blockIdx.x * 4 + (threadIdx.x >> 6);
    int lane = threadIdx.x & 63;
    if (i >= n) return;
    float hf = af[(size_t)i * 64 + lane] + bf[lane];
    float s0 = as6[i * 6 + 0], s1 = as6[i * 6 + 1], s2 = as6[i * 6 + 2];
    float s3 = as6[i * 6 + 3], s4 = as6[i * 6 + 4], s5 = as6[i * 6 + 5];
    float hs = s0 * Ws[0 * 64 + lane] + s1 * Ws[1 * 64 + lane] +
               s2 * Ws[2 * 64 + lane] + s3 * Ws[3 * 64 + lane] +
               s4 * Ws[4 * 64 + lane] + s5 * Ws[5 * 64 + lane] + bs[lane];
    out_hf[(size_t)i * 64 + lane] = hf;
    out_hs[(size_t)i * 64 + lane] = hs;

    float fa = hf * cw[6];  // attr * a_a * 2
    float sa = hs * cw[7];  // struc * a_s * 2
    float p[7];
    #pragma unroll
    for (int j = 0; j < 7; j++) {
        float v = fa * Wr[lane * 7 + j] + sa * Wr[(64 + lane) * 7 + j];
        #pragma unroll
        for (int off = 32; off; off >>= 1) v += __shfl_xor(v, off);
        p[j] = v;
    }
    if (lane == 0) {
        float d = dinv[i];
        float d2 = d * d;
        #pragma unroll
        for (int j = 0; j < 7; j++) {
            xr[(size_t)i * 8 + j] = p[j];
            ay[(size_t)i * 8 + j] = p[j] * d2;
        }
    }
}

// Edge scatter for branch 3: 8 lanes per edge (j<7 active).
__global__ __launch_bounds__(256) void scatter_y_k(const void* __restrict__ ei,
                                                   const float* __restrict__ xr,
                                                   const float* __restrict__ dinv,
                                                   const float* __restrict__ cw,
                                                   float* __restrict__ ay, int E) {
    int t = blockIdx.x * 256 + threadIdx.x;
    int e = t >> 3, j = t & 7;
    if (e >= E) return;
    int flag = ((const int*)cw)[8];
    int r, c;
    load_edge(ei, e, E, flag, r, c);
    if (j < 7) {
        float nrm = dinv[r] * dinv[c];
        atomicAdd(&ay[(size_t)c * 8 + j], xr[(size_t)r * 8 + j] * nrm);
    }
}

__global__ void finy_k(const float* __restrict__ ay, const float* __restrict__ br,
                       float* __restrict__ out_y, int n) {
    int t = blockIdx.x * 256 + threadIdx.x;
    int i = t >> 3, j = t & 7;
    if (i >= n || j >= 7) return;
    out_y[(size_t)i * 7 + j] = ay[(size_t)i * 8 + j] + br[j];
}

extern "C" void kernel_launch(void* const* d_in, const int* in_sizes, int n_in,
                              void* d_out, int out_size, void* d_ws, size_t ws_size,
                              hipStream_t stream) {
    const float* feature   = (const float*)d_in[0];
    const float* structure = (const float*)d_in[1];
    const void*  ei        = d_in[2];
    const float* Wf  = (const float*)d_in[3];
    const float* bf  = (const float*)d_in[4];
    const float* Ws  = (const float*)d_in[5];
    const float* bs  = (const float*)d_in[6];
    const float* Wr  = (const float*)d_in[7];
    const float* br  = (const float*)d_in[8];
    const float* emb = (const float*)d_in[9];
    const float* embW = (const float*)d_in[10];
    const float* alpha_s = (const float*)d_in[11];
    const float* alpha_a = (const float*)d_in[12];

    const int N = in_sizes[0] / 512;
    const int E = in_sizes[2] / 2;

    float* ws = (float*)d_ws;
    size_t XF = 0;
    size_t AF = XF + (size_t)N * 64;
    size_t AS6 = AF + (size_t)N * 64;
    size_t XR = AS6 + (size_t)N * 6;
    size_t AY = XR + (size_t)N * 8;
    size_t DINV = AY + (size_t)N * 8;
    size_t DEG = DINV + (size_t)N;
    size_t CONST = DEG + (size_t)N;
    float* xf = ws + XF;
    float* af = ws + AF;
    float* as6 = ws + AS6;
    float* xr = ws + XR;
    float* ay = ws + AY;
    float* dinv = ws + DINV;
    unsigned* deg = (unsigned*)(ws + DEG);
    float* cw = ws + CONST;

    // zero deg histogram + consts (incl. dtype flag) every call (ws not re-poisoned)
    hipMemsetAsync(deg, 0, ((size_t)N + 16) * 4, stream);
    detect_k<<<(E + 255) / 256, 256, 0, stream>>>((const int*)ei, (int*)(cw + 8), E);
    setup_k<<<1, 64, 0, stream>>>(emb, embW, alpha_s, alpha_a, cw);
    deg_k<<<(E + 255) / 256, 256, 0, stream>>>(ei, cw, deg, E);
    dinv_k<<<(N + 255) / 256, 256, 0, stream>>>(deg, dinv, N);
    gemm_f_k<<<(N + 15) / 16, 256, 0, stream>>>(feature, Wf, xf, N);
    init_fs_k<<<(N + 3) / 4, 256, 0, stream>>>(xf, structure, dinv, cw, af, as6, N);
    scatter_fs_k<<<(E + 3) / 4, 256, 0, stream>>>(ei, xf, structure, dinv, cw, af, as6, E);

    float* out_hf = (float*)d_out;
    float* out_hs = out_hf + (size_t)N * 64;
    float* out_y  = out_hf + (size_t)N * 128;
    finalize1_k<<<(N + 3) / 4, 256, 0, stream>>>(af, as6, bf, Ws, bs, Wr, dinv, cw,
                                                 out_hf, out_hs, xr, ay, N);
    scatter_y_k<<<((size_t)E * 8 + 255) / 256, 256, 0, stream>>>(ei, xr, dinv, cw, ay, E);
    finy_k<<<((size_t)N * 8 + 255) / 256, 256, 0, stream>>>(ay, br, out_y, N);
}

// Round 3
// 1048.851 us; speedup vs baseline: 1.4387x; 1.4387x over previous
//
#include <hip/hip_runtime.h>
#include <hip/hip_bf16.h>
#include <string.h>

// MORAL: 3x GCNConv on N=100000 nodes, E=1.6M edges. All fp32 I/O.
// Branch1: xf = feature @ W_f via split-bf16 MFMA (Ah*Wh + Ah*Wl + Al*Wh),
// then aggregate. Branch2: aggregate 6-dim gated structure, then W_s.
// Branch3: project(128->7) then aggregate. fp32 accumulators in ws.

typedef __attribute__((ext_vector_type(8))) short bf16x8;
typedef __attribute__((ext_vector_type(4))) float f32x4;

__device__ __forceinline__ unsigned short f2bf(float x) {
    union { __hip_bfloat16 b; unsigned short u; } cv;
    cv.b = __float2bfloat16(x);
    return cv.u;
}
__device__ __forceinline__ float bf2f(unsigned short u) {
    union { unsigned u32; float f; } cv;
    cv.u32 = ((unsigned)u) << 16;
    return cv.f;
}

__global__ void detect_k(const int* __restrict__ ei32, int* __restrict__ flag, int E) {
    int i = blockIdx.x * 256 + threadIdx.x;
    bool nz = (i < E) && (ei32[2 * i + 1] != 0);
    if (__any(nz) && (threadIdx.x & 63) == 0) atomicOr(flag, 1);
}

__global__ void setup_k(const float* __restrict__ emb,
                        const float* __restrict__ embW,
                        const float* __restrict__ alpha_s,
                        const float* __restrict__ alpha_a,
                        float* __restrict__ cw) {
    int lane = threadIdx.x;  // 64 threads
    float w = embW[lane];
    #pragma unroll
    for (int k = 0; k < 6; k++) {
        float p = emb[k * 64 + lane] * w;
        #pragma unroll
        for (int off = 32; off; off >>= 1) p += __shfl_xor(p, off);
        if (lane == 0) cw[k] = (p < 0.0f) ? 0.0f : 1.0f;  // sigmoid(p)<0.5 <=> p<0
    }
    if (lane == 0) {
        float s = alpha_s[0];
        float a = alpha_a[0];
        float inv = 1.0f / (fabsf(s) + fabsf(a));
        cw[6] = 2.0f * a * inv;  // scale on attr (h_f)
        cw[7] = 2.0f * s * inv;  // scale on struc (h_s)
    }
}

__device__ __forceinline__ void load_edge(const void* ei, int e, int E, int flag,
                                          int& r, int& c) {
    if (flag) {
        const int* p = (const int*)ei;
        r = p[e]; c = p[E + e];
    } else {
        const long long* p = (const long long*)ei;
        r = (int)p[e]; c = (int)p[(size_t)E + e];
    }
}

__global__ void deg_k(const void* __restrict__ ei, const float* __restrict__ cw,
                      unsigned* __restrict__ deg, int E) {
    int e = blockIdx.x * 256 + threadIdx.x;
    if (e >= E) return;
    int flag = ((const int*)cw)[8];
    int c = flag ? ((const int*)ei)[E + e]
                 : (int)((const long long*)ei)[(size_t)E + e];
    atomicAdd(&deg[c], 1u);
}

__global__ void dinv_k(const unsigned* __restrict__ deg, float* __restrict__ dinv, int n) {
    int i = blockIdx.x * 256 + threadIdx.x;
    if (i < n) dinv[i] = rsqrtf((float)deg[i] + 1.0f);  // +1 = self-loop
}

// Split+transpose W_f once: Wth/Wtl[c][k] bf16 bits, k contiguous.
__global__ void prep_w_k(const float* __restrict__ Wf,
                         unsigned short* __restrict__ WthG,
                         unsigned short* __restrict__ WtlG) {
    int idx = blockIdx.x * 256 + threadIdx.x;
    if (idx >= 512 * 64) return;
    int k = idx >> 6, c = idx & 63;
    float w = Wf[idx];
    unsigned short h = f2bf(w);
    unsigned short l = f2bf(w - bf2f(h));
    WthG[c * 512 + k] = h;
    WtlG[c * 512 + k] = l;
}

// xf = feature @ W_f via MFMA split-bf16. Block: 128 rows x 64 cols, BK=64.
// 4 waves, each 32 rows x 64 cols (2 m-tiles x 4 n-tiles of 16x16x32).
// LDS XOR swizzle: byte ^= (row&7)<<4 (st_16x32-style) for conflict-free b128.
__global__ __launch_bounds__(256) void gemm_f_mfma(const float* __restrict__ feat,
                                                   const unsigned short* __restrict__ WthG,
                                                   const unsigned short* __restrict__ WtlG,
                                                   float* __restrict__ xf, int n) {
    __shared__ unsigned short Ah[128 * 64];
    __shared__ unsigned short Al[128 * 64];
    __shared__ unsigned short Bh[64 * 64];
    __shared__ unsigned short Bl[64 * 64];

    const int tid = threadIdx.x;
    const int blk = blockIdx.x;
    const int w = tid >> 6, l = tid & 63;
    const int lr = l & 15, lg = l >> 4;

    f32x4 acc[2][4];
    #pragma unroll
    for (int m = 0; m < 2; m++)
        #pragma unroll
        for (int nt = 0; nt < 4; nt++) acc[m][nt] = (f32x4)(0.0f);

    // staging coords
    const int sr = tid >> 1, shalf = tid & 1;       // A: row, k-half
    const int swc = tid >> 2, swq = tid & 3;        // W: col, quarter
    const int gr_ld = min(blk * 128 + sr, n - 1);
    const float* asrc = feat + (size_t)gr_ld * 512 + shalf * 32;

    for (int k0 = 0; k0 < 512; k0 += 64) {
        // ---- stage A chunk [128][64] fp32 -> bf16 hi/lo in LDS ----
        {
            const float4* s4 = (const float4*)(asrc + k0);
            int base = sr * 128 + shalf * 64;
            int sw = (sr & 7) << 4;
            #pragma unroll
            for (int g = 0; g < 8; g++) {
                float4 v = s4[g];
                ushort4 h, lo;
                h.x = f2bf(v.x); lo.x = f2bf(v.x - bf2f(h.x));
                h.y = f2bf(v.y); lo.y = f2bf(v.y - bf2f(h.y));
                h.z = f2bf(v.z); lo.z = f2bf(v.z - bf2f(h.z));
                h.w = f2bf(v.w); lo.w = f2bf(v.w - bf2f(h.w));
                int off = (base + g * 8) ^ sw;
                *(ushort4*)((char*)Ah + off) = h;
                *(ushort4*)((char*)Al + off) = lo;
            }
        }
        // ---- stage W chunk [64 cols][64 k] bf16 hi/lo ----
        {
            int sw = (swc & 7) << 4;
            const unsigned short* wh = WthG + swc * 512 + k0;
            const unsigned short* wl = WtlG + swc * 512 + k0;
            #pragma unroll
            for (int s = 0; s < 2; s++) {
                int ko16 = swq * 2 + s;  // 16B slot 0..7
                uint4 vh = *(const uint4*)(wh + ko16 * 8);
                uint4 vl = *(const uint4*)(wl + ko16 * 8);
                int off = (swc * 128 + ko16 * 16) ^ sw;
                *(uint4*)((char*)Bh + off) = vh;
                *(uint4*)((char*)Bl + off) = vl;
            }
        }
        __syncthreads();
        // ---- MFMA: 2 ksteps x 2 m x 4 n x 3 split-terms ----
        int swl = (lr & 7) << 4;
        #pragma unroll
        for (int ks = 0; ks < 2; ks++) {
            int koff = ks * 64 + lg * 16;
            int ra = ((w * 32 + lr) * 128 + koff) ^ swl;
            bf16x8 ah0 = *(const bf16x8*)((const char*)Ah + ra);
            bf16x8 al0 = *(const bf16x8*)((const char*)Al + ra);
            bf16x8 ah1 = *(const bf16x8*)((const char*)Ah + ra + 16 * 128);
            bf16x8 al1 = *(const bf16x8*)((const char*)Al + ra + 16 * 128);
            #pragma unroll
            for (int nt = 0; nt < 4; nt++) {
                int cb = ((nt * 16 + lr) * 128 + koff) ^ swl;
                bf16x8 bh = *(const bf16x8*)((const char*)Bh + cb);
                bf16x8 bl = *(const bf16x8*)((const char*)Bl + cb);
                acc[0][nt] = __builtin_amdgcn_mfma_f32_16x16x32_bf16(ah0, bh, acc[0][nt], 0, 0, 0);
                acc[0][nt] = __builtin_amdgcn_mfma_f32_16x16x32_bf16(ah0, bl, acc[0][nt], 0, 0, 0);
                acc[0][nt] = __builtin_amdgcn_mfma_f32_16x16x32_bf16(al0, bh, acc[0][nt], 0, 0, 0);
                acc[1][nt] = __builtin_amdgcn_mfma_f32_16x16x32_bf16(ah1, bh, acc[1][nt], 0, 0, 0);
                acc[1][nt] = __builtin_amdgcn_mfma_f32_16x16x32_bf16(ah1, bl, acc[1][nt], 0, 0, 0);
                acc[1][nt] = __builtin_amdgcn_mfma_f32_16x16x32_bf16(al1, bh, acc[1][nt], 0, 0, 0);
            }
        }
        __syncthreads();
    }
    // ---- store: C/D layout col=lane&15, row=(lane>>4)*4+reg (m89) ----
    #pragma unroll
    for (int m = 0; m < 2; m++) {
        int row0 = blk * 128 + w * 32 + m * 16 + lg * 4;
        #pragma unroll
        for (int nt = 0; nt < 4; nt++) {
            #pragma unroll
            for (int reg = 0; reg < 4; reg++) {
                int gr = row0 + reg;
                if (gr < n) xf[(size_t)gr * 64 + nt * 16 + lr] = acc[m][nt][reg];
            }
        }
    }
}

// Self-loop init: af[i] = xf[i]*dinv[i]^2 ; as6[i][k] = structure[i][k]*gate[k]*dinv^2
__global__ __launch_bounds__(256) void init_fs_k(const float* __restrict__ xf,
                                                 const float* __restrict__ structure,
                                                 const float* __restrict__ dinv,
                                                 const float* __restrict__ cw,
                                                 float* __restrict__ af,
                                                 float* __restrict__ as6, int n) {
    int i = blockIdx.x * 4 + (threadIdx.x >> 6);
    int lane = threadIdx.x & 63;
    if (i >= n) return;
    float d = dinv[i];
    float d2 = d * d;
    af[(size_t)i * 64 + lane] = xf[(size_t)i * 64 + lane] * d2;
    if (lane < 6)
        as6[i * 6 + lane] = structure[i * 6 + lane] * cw[lane] * d2;
}

// Edge scatter for branches 1 & 2: one wave per edge.
__global__ __launch_bounds__(256) void scatter_fs_k(const void* __restrict__ ei,
                                                    const float* __restrict__ xf,
                                                    const float* __restrict__ structure,
                                                    const float* __restrict__ dinv,
                                                    const float* __restrict__ cw,
                                                    float* __restrict__ af,
                                                    float* __restrict__ as6, int E) {
    int e = blockIdx.x * 4 + (threadIdx.x >> 6);
    int lane = threadIdx.x & 63;
    if (e >= E) return;
    int flag = ((const int*)cw)[8];
    int r, c;
    load_edge(ei, e, E, flag, r, c);
    float nrm = dinv[r] * dinv[c];
    atomicAdd(&af[(size_t)c * 64 + lane], xf[(size_t)r * 64 + lane] * nrm);
    if (lane < 6)
        atomicAdd(&as6[c * 6 + lane], structure[r * 6 + lane] * cw[lane] * nrm);
}

// Finalize h_f, h_s and project to xr = x @ W_r (7), init ay self-loop.
__global__ __launch_bounds__(256) void finalize1_k(const float* __restrict__ af,
                                                   const float* __restrict__ as6,
                                                   const float* __restrict__ bf,
                                                   const float* __restrict__ Ws,
                                                   const float* __restrict__ bs,
                                                   const float* __restrict__ Wr,
                                                   const float* __restrict__ dinv,
                                                   const float* __restrict__ cw,
                                                   float* __restrict__ out_hf,
                                                   float* __restrict__ out_hs,
                                                   float* __restrict__ xr,
                                                   float* __restrict__ ay, int n) {
    int i = blockIdx.x * 4 + (threadIdx.x >> 6);
    int lane = threadIdx.x & 63;
    if (i >= n) return;
    float hf = af[(size_t)i * 64 + lane] + bf[lane];
    float s0 = as6[i * 6 + 0], s1 = as6[i * 6 + 1], s2 = as6[i * 6 + 2];
    float s3 = as6[i * 6 + 3], s4 = as6[i * 6 + 4], s5 = as6[i * 6 + 5];
    float hs = s0 * Ws[0 * 64 + lane] + s1 * Ws[1 * 64 + lane] +
               s2 * Ws[2 * 64 + lane] + s3 * Ws[3 * 64 + lane] +
               s4 * Ws[4 * 64 + lane] + s5 * Ws[5 * 64 + lane] + bs[lane];
    out_hf[(size_t)i * 64 + lane] = hf;
    out_hs[(size_t)i * 64 + lane] = hs;

    float fa = hf * cw[6];  // attr * a_a * 2
    float sa = hs * cw[7];  // struc * a_s * 2
    float p[7];
    #pragma unroll
    for (int j = 0; j < 7; j++) {
        float v = fa * Wr[lane * 7 + j] + sa * Wr[(64 + lane) * 7 + j];
        #pragma unroll
        for (int off = 32; off; off >>= 1) v += __shfl_xor(v, off);
        p[j] = v;
    }
    if (lane == 0) {
        float d = dinv[i];
        float d2 = d * d;
        #pragma unroll
        for (int j = 0; j < 7; j++) {
            xr[(size_t)i * 8 + j] = p[j];
            ay[(size_t)i * 8 + j] = p[j] * d2;
        }
    }
}

// Edge scatter for branch 3: 8 lanes per edge (j<7 active).
__global__ __launch_bounds__(256) void scatter_y_k(const void* __restrict__ ei,
                                                   const float* __restrict__ xr,
                                                   const float* __restrict__ dinv,
                                                   const float* __restrict__ cw,
                                                   float* __restrict__ ay, int E) {
    int t = blockIdx.x * 256 + threadIdx.x;
    int e = t >> 3, j = t & 7;
    if (e >= E) return;
    int flag = ((const int*)cw)[8];
    int r, c;
    load_edge(ei, e, E, flag, r, c);
    if (j < 7) {
        float nrm = dinv[r] * dinv[c];
        atomicAdd(&ay[(size_t)c * 8 + j], xr[(size_t)r * 8 + j] * nrm);
    }
}

__global__ void finy_k(const float* __restrict__ ay, const float* __restrict__ br,
                       float* __restrict__ out_y, int n) {
    int t = blockIdx.x * 256 + threadIdx.x;
    int i = t >> 3, j = t & 7;
    if (i >= n || j >= 7) return;
    out_y[(size_t)i * 7 + j] = ay[(size_t)i * 8 + j] + br[j];
}

extern "C" void kernel_launch(void* const* d_in, const int* in_sizes, int n_in,
                              void* d_out, int out_size, void* d_ws, size_t ws_size,
                              hipStream_t stream) {
    const float* feature   = (const float*)d_in[0];
    const float* structure = (const float*)d_in[1];
    const void*  ei        = d_in[2];
    const float* Wf  = (const float*)d_in[3];
    const float* bf  = (const float*)d_in[4];
    const float* Ws  = (const float*)d_in[5];
    const float* bs  = (const float*)d_in[6];
    const float* Wr  = (const float*)d_in[7];
    const float* br  = (const float*)d_in[8];
    const float* emb = (const float*)d_in[9];
    const float* embW = (const float*)d_in[10];
    const float* alpha_s = (const float*)d_in[11];
    const float* alpha_a = (const float*)d_in[12];

    const int N = in_sizes[0] / 512;
    const int E = in_sizes[2] / 2;

    float* ws = (float*)d_ws;
    size_t XF = 0;
    size_t AF = XF + (size_t)N * 64;
    size_t AS6 = AF + (size_t)N * 64;
    size_t XR = AS6 + (size_t)N * 6;
    size_t AY = XR + (size_t)N * 8;
    size_t DINV = AY + (size_t)N * 8;
    size_t DEG = DINV + (size_t)N;
    size_t CONST = DEG + (size_t)N;
    size_t WTS = CONST + 16;  // W_f split/transposed: 2 x 32768 ushorts = 32768 floats
    float* xf = ws + XF;
    float* af = ws + AF;
    float* as6 = ws + AS6;
    float* xr = ws + XR;
    float* ay = ws + AY;
    float* dinv = ws + DINV;
    unsigned* deg = (unsigned*)(ws + DEG);
    float* cw = ws + CONST;
    unsigned short* WthG = (unsigned short*)(ws + WTS);
    unsigned short* WtlG = WthG + 512 * 64;

    // zero deg histogram + consts (incl. dtype flag) every call (ws not re-poisoned)
    hipMemsetAsync(deg, 0, ((size_t)N + 16) * 4, stream);
    detect_k<<<(E + 255) / 256, 256, 0, stream>>>((const int*)ei, (int*)(cw + 8), E);
    setup_k<<<1, 64, 0, stream>>>(emb, embW, alpha_s, alpha_a, cw);
    deg_k<<<(E + 255) / 256, 256, 0, stream>>>(ei, cw, deg, E);
    dinv_k<<<(N + 255) / 256, 256, 0, stream>>>(deg, dinv, N);
    prep_w_k<<<(512 * 64 + 255) / 256, 256, 0, stream>>>(Wf, WthG, WtlG);
    gemm_f_mfma<<<(N + 127) / 128, 256, 0, stream>>>(feature, WthG, WtlG, xf, N);
    init_fs_k<<<(N + 3) / 4, 256, 0, stream>>>(xf, structure, dinv, cw, af, as6, N);
    scatter_fs_k<<<(E + 3) / 4, 256, 0, stream>>>(ei, xf, structure, dinv, cw, af, as6, E);

    float* out_hf = (float*)d_out;
    float* out_hs = out_hf + (size_t)N * 64;
    float* out_y  = out_hf + (size_t)N * 128;
    finalize1_k<<<(N + 3) / 4, 256, 0, stream>>>(af, as6, bf, Ws, bs, Wr, dinv, cw,
                                                 out_hf, out_hs, xr, ay, N);
    scatter_y_k<<<((size_t)E * 8 + 255) / 256, 256, 0, stream>>>(ei, xr, dinv, cw, ay, E);
    finy_k<<<((size_t)N * 8 + 255) / 256, 256, 0, stream>>>(ay, br, out_y, N);
}

// Round 4
// 705.647 us; speedup vs baseline: 2.1384x; 1.4864x over previous
//
#include <hip/hip_runtime.h>
#include <hip/hip_bf16.h>

// MORAL: 3x GCNConv, N=100000, E=1.6M, fp32 I/O.
// CSR-by-destination built on device (deg -> scan -> fill), then gather-based
// aggregation (no atomics in hot loops). Pre-scaling by dinv[r] folds the edge
// norm into the operands: out[c] = (sum_{r in in(c)} x[r]*dinv[r] + x[c]*dinv[c]) * dinv[c].
// Branch1 GEMM: split-bf16 MFMA (Ah*Wh + Ah*Wl + Al*Wh).

typedef __attribute__((ext_vector_type(8))) short bf16x8;
typedef __attribute__((ext_vector_type(4))) float f32x4;

__device__ __forceinline__ unsigned short f2bf(float x) {
    union { __hip_bfloat16 b; unsigned short u; } cv;
    cv.b = __float2bfloat16(x);
    return cv.u;
}
__device__ __forceinline__ float bf2f(unsigned short u) {
    union { unsigned u32; float f; } cv;
    cv.u32 = ((unsigned)u) << 16;
    return cv.f;
}

__global__ void detect_k(const int* __restrict__ ei32, int* __restrict__ flag, int E) {
    int i = blockIdx.x * 256 + threadIdx.x;
    bool nz = (i < E) && (ei32[2 * i + 1] != 0);
    if (__any(nz) && (threadIdx.x & 63) == 0) atomicOr(flag, 1);
}

__global__ void setup_k(const float* __restrict__ emb,
                        const float* __restrict__ embW,
                        const float* __restrict__ alpha_s,
                        const float* __restrict__ alpha_a,
                        float* __restrict__ cw) {
    int lane = threadIdx.x;  // 64 threads
    float w = embW[lane];
    #pragma unroll
    for (int k = 0; k < 6; k++) {
        float p = emb[k * 64 + lane] * w;
        #pragma unroll
        for (int off = 32; off; off >>= 1) p += __shfl_xor(p, off);
        if (lane == 0) cw[k] = (p < 0.0f) ? 0.0f : 1.0f;  // sigmoid(p)<0.5 <=> p<0
    }
    if (lane == 0) {
        float s = alpha_s[0];
        float a = alpha_a[0];
        float inv = 1.0f / (fabsf(s) + fabsf(a));
        cw[6] = 2.0f * a * inv;  // scale on attr (h_f)
        cw[7] = 2.0f * s * inv;  // scale on struc (h_s)
    }
}

__device__ __forceinline__ void load_edge(const void* ei, int e, int E, int flag,
                                          int& r, int& c) {
    if (flag) {
        const int* p = (const int*)ei;
        r = p[e]; c = p[E + e];
    } else {
        const long long* p = (const long long*)ei;
        r = (int)p[e]; c = (int)p[(size_t)E + e];
    }
}

__global__ void deg_k(const void* __restrict__ ei, const float* __restrict__ cw,
                      unsigned* __restrict__ deg, int E) {
    int e = blockIdx.x * 256 + threadIdx.x;
    if (e >= E) return;
    int flag = ((const int*)cw)[8];
    int c = flag ? ((const int*)ei)[E + e]
                 : (int)((const long long*)ei)[(size_t)E + e];
    atomicAdd(&deg[c], 1u);
}

__global__ void dinv_k(const unsigned* __restrict__ deg, float* __restrict__ dinv, int n) {
    int i = blockIdx.x * 256 + threadIdx.x;
    if (i < n) dinv[i] = rsqrtf((float)deg[i] + 1.0f);  // +1 = self-loop
}

// ---- CSR build: block-local exclusive scan + block totals ----
__global__ __launch_bounds__(256) void scan1_k(const unsigned* __restrict__ deg,
                                               unsigned* __restrict__ rowptr,
                                               unsigned* __restrict__ part, int n) {
    __shared__ unsigned s[256];
    int i = blockIdx.x * 256 + threadIdx.x;
    unsigned v = (i < n) ? deg[i] : 0u;
    s[threadIdx.x] = v;
    __syncthreads();
    #pragma unroll
    for (int off = 1; off < 256; off <<= 1) {
        unsigned t = (threadIdx.x >= off) ? s[threadIdx.x - off] : 0u;
        __syncthreads();
        s[threadIdx.x] += t;
        __syncthreads();
    }
    if (i < n) rowptr[i] = s[threadIdx.x] - v;  // local exclusive
    if (threadIdx.x == 255) part[blockIdx.x] = s[255];
}

// exclusive-scan the block totals (one wave, shfl scan over 64-chunks)
__global__ void scan2_k(unsigned* __restrict__ part, int nb) {
    int lane = threadIdx.x;  // 64
    unsigned run = 0;
    for (int base = 0; base < nb; base += 64) {
        unsigned v = (base + lane < nb) ? part[base + lane] : 0u;
        unsigned orig = v;
        #pragma unroll
        for (int off = 1; off < 64; off <<= 1) {
            unsigned t = __shfl_up(v, off);
            if (lane >= off) v += t;
        }
        if (base + lane < nb) part[base + lane] = run + v - orig;
        run += __shfl(v, 63);
    }
}

__global__ void scan3_k(unsigned* __restrict__ rowptr, const unsigned* __restrict__ part,
                        int n, int E) {
    int i = blockIdx.x * 256 + threadIdx.x;
    if (i < n) rowptr[i] += part[blockIdx.x];
    if (i == 0) rowptr[n] = (unsigned)E;
}

__global__ void fill_k(const void* __restrict__ ei, const float* __restrict__ cw,
                       const unsigned* __restrict__ rowptr, unsigned* __restrict__ cursor,
                       int* __restrict__ srcidx, int E) {
    int e = blockIdx.x * 256 + threadIdx.x;
    if (e >= E) return;
    int flag = ((const int*)cw)[8];
    int r, c;
    load_edge(ei, e, E, flag, r, c);
    unsigned pos = atomicAdd(&cursor[c], 1u);
    srcidx[rowptr[c] + pos] = r;
}

// Split+transpose W_f once: Wth/Wtl[c][k] bf16 bits, k contiguous.
__global__ void prep_w_k(const float* __restrict__ Wf,
                         unsigned short* __restrict__ WthG,
                         unsigned short* __restrict__ WtlG) {
    int idx = blockIdx.x * 256 + threadIdx.x;
    if (idx >= 512 * 64) return;
    int k = idx >> 6, c = idx & 63;
    float w = Wf[idx];
    unsigned short h = f2bf(w);
    unsigned short l = f2bf(w - bf2f(h));
    WthG[c * 512 + k] = h;
    WtlG[c * 512 + k] = l;
}

// xs = (feature @ W_f) * dinv[row], via MFMA split-bf16. Block: 128x64, BK=64.
__global__ __launch_bounds__(256) void gemm_f_mfma(const float* __restrict__ feat,
                                                   const unsigned short* __restrict__ WthG,
                                                   const unsigned short* __restrict__ WtlG,
                                                   const float* __restrict__ dinv,
                                                   float* __restrict__ xs, int n) {
    __shared__ unsigned short Ah[128 * 64];
    __shared__ unsigned short Al[128 * 64];
    __shared__ unsigned short Bh[64 * 64];
    __shared__ unsigned short Bl[64 * 64];

    const int tid = threadIdx.x;
    const int blk = blockIdx.x;
    const int w = tid >> 6, l = tid & 63;
    const int lr = l & 15, lg = l >> 4;

    f32x4 acc[2][4];
    #pragma unroll
    for (int m = 0; m < 2; m++)
        #pragma unroll
        for (int nt = 0; nt < 4; nt++) acc[m][nt] = (f32x4)(0.0f);

    const int sr = tid >> 1, shalf = tid & 1;       // A: row, k-half
    const int swc = tid >> 2, swq = tid & 3;        // W: col, quarter
    const int gr_ld = min(blk * 128 + sr, n - 1);
    const float* asrc = feat + (size_t)gr_ld * 512 + shalf * 32;

    for (int k0 = 0; k0 < 512; k0 += 64) {
        {
            const float4* s4 = (const float4*)(asrc + k0);
            int base = sr * 128 + shalf * 64;
            int sw = (sr & 7) << 4;
            #pragma unroll
            for (int g = 0; g < 8; g++) {
                float4 v = s4[g];
                ushort4 h, lo;
                h.x = f2bf(v.x); lo.x = f2bf(v.x - bf2f(h.x));
                h.y = f2bf(v.y); lo.y = f2bf(v.y - bf2f(h.y));
                h.z = f2bf(v.z); lo.z = f2bf(v.z - bf2f(h.z));
                h.w = f2bf(v.w); lo.w = f2bf(v.w - bf2f(h.w));
                int off = (base + g * 8) ^ sw;
                *(ushort4*)((char*)Ah + off) = h;
                *(ushort4*)((char*)Al + off) = lo;
            }
        }
        {
            int sw = (swc & 7) << 4;
            const unsigned short* wh = WthG + swc * 512 + k0;
            const unsigned short* wl = WtlG + swc * 512 + k0;
            #pragma unroll
            for (int s = 0; s < 2; s++) {
                int ko16 = swq * 2 + s;
                uint4 vh = *(const uint4*)(wh + ko16 * 8);
                uint4 vl = *(const uint4*)(wl + ko16 * 8);
                int off = (swc * 128 + ko16 * 16) ^ sw;
                *(uint4*)((char*)Bh + off) = vh;
                *(uint4*)((char*)Bl + off) = vl;
            }
        }
        __syncthreads();
        int swl = (lr & 7) << 4;
        #pragma unroll
        for (int ks = 0; ks < 2; ks++) {
            int koff = ks * 64 + lg * 16;
            int ra = ((w * 32 + lr) * 128 + koff) ^ swl;
            bf16x8 ah0 = *(const bf16x8*)((const char*)Ah + ra);
            bf16x8 al0 = *(const bf16x8*)((const char*)Al + ra);
            bf16x8 ah1 = *(const bf16x8*)((const char*)Ah + ra + 16 * 128);
            bf16x8 al1 = *(const bf16x8*)((const char*)Al + ra + 16 * 128);
            #pragma unroll
            for (int nt = 0; nt < 4; nt++) {
                int cb = ((nt * 16 + lr) * 128 + koff) ^ swl;
                bf16x8 bh = *(const bf16x8*)((const char*)Bh + cb);
                bf16x8 bl = *(const bf16x8*)((const char*)Bl + cb);
                acc[0][nt] = __builtin_amdgcn_mfma_f32_16x16x32_bf16(ah0, bh, acc[0][nt], 0, 0, 0);
                acc[0][nt] = __builtin_amdgcn_mfma_f32_16x16x32_bf16(ah0, bl, acc[0][nt], 0, 0, 0);
                acc[0][nt] = __builtin_amdgcn_mfma_f32_16x16x32_bf16(al0, bh, acc[0][nt], 0, 0, 0);
                acc[1][nt] = __builtin_amdgcn_mfma_f32_16x16x32_bf16(ah1, bh, acc[1][nt], 0, 0, 0);
                acc[1][nt] = __builtin_amdgcn_mfma_f32_16x16x32_bf16(ah1, bl, acc[1][nt], 0, 0, 0);
                acc[1][nt] = __builtin_amdgcn_mfma_f32_16x16x32_bf16(al1, bh, acc[1][nt], 0, 0, 0);
            }
        }
        __syncthreads();
    }
    // C/D layout: col=lane&15, row=(lane>>4)*4+reg (m89). Scale by dinv[row].
    #pragma unroll
    for (int m = 0; m < 2; m++) {
        int row0 = blk * 128 + w * 32 + m * 16 + lg * 4;
        #pragma unroll
        for (int reg = 0; reg < 4; reg++) {
            int gr = row0 + reg;
            if (gr < n) {
                float dv = dinv[gr];
                #pragma unroll
                for (int nt = 0; nt < 4; nt++)
                    xs[(size_t)gr * 64 + nt * 16 + lr] = acc[m][nt][reg] * dv;
            }
        }
    }
}

// ss6[i][k] = structure[i][k] * gate[k] * dinv[i]  (padded stride 8)
__global__ void ss6_k(const float* __restrict__ structure, const float* __restrict__ dinv,
                      const float* __restrict__ cw, float* __restrict__ ss6, int n) {
    int idx = blockIdx.x * 256 + threadIdx.x;
    if (idx >= n * 8) return;
    int i = idx >> 3, k = idx & 7;
    float v = (k < 6) ? structure[i * 6 + k] * cw[k] * dinv[i] : 0.0f;
    ss6[idx] = v;
}

// Gather-aggregate branches 1&2 + fused epilogue: h_f, h_s outputs and
// ps[i][j] = (x @ W_r)[i][j] * dinv[i] for branch 3.
__global__ __launch_bounds__(256) void agg_fs_k(const float* __restrict__ xs,
                                                const float* __restrict__ ss6,
                                                const int* __restrict__ srcidx,
                                                const unsigned* __restrict__ rowptr,
                                                const float* __restrict__ dinv,
                                                const float* __restrict__ cw,
                                                const float* __restrict__ bfv,
                                                const float* __restrict__ Ws,
                                                const float* __restrict__ bs,
                                                const float* __restrict__ Wr,
                                                float* __restrict__ out_hf,
                                                float* __restrict__ out_hs,
                                                float* __restrict__ ps, int n) {
    int i = blockIdx.x * 4 + (threadIdx.x >> 6);
    int lane = threadIdx.x & 63;
    if (i >= n) return;
    unsigned e = rowptr[i], s1 = rowptr[i + 1];
    float acc = xs[(size_t)i * 64 + lane];          // self-loop term
    float a6 = (lane < 6) ? ss6[i * 8 + lane] : 0.0f;
    for (; e + 4 <= s1; e += 4) {
        int r0 = srcidx[e], r1 = srcidx[e + 1], r2 = srcidx[e + 2], r3 = srcidx[e + 3];
        float v0 = xs[(size_t)r0 * 64 + lane];
        float v1 = xs[(size_t)r1 * 64 + lane];
        float v2 = xs[(size_t)r2 * 64 + lane];
        float v3 = xs[(size_t)r3 * 64 + lane];
        acc += (v0 + v1) + (v2 + v3);
        if (lane < 6)
            a6 += (ss6[r0 * 8 + lane] + ss6[r1 * 8 + lane]) +
                  (ss6[r2 * 8 + lane] + ss6[r3 * 8 + lane]);
    }
    for (; e < s1; e++) {
        int r = srcidx[e];
        acc += xs[(size_t)r * 64 + lane];
        if (lane < 6) a6 += ss6[r * 8 + lane];
    }
    float di = dinv[i];
    float hf = acc * di + bfv[lane];
    float hs = bs[lane];
    #pragma unroll
    for (int k = 0; k < 6; k++) hs += __shfl(a6, k) * di * Ws[k * 64 + lane];
    out_hf[(size_t)i * 64 + lane] = hf;
    out_hs[(size_t)i * 64 + lane] = hs;

    float fa = hf * cw[6];  // attr * a_a * 2
    float sa = hs * cw[7];  // struc * a_s * 2
    #pragma unroll
    for (int j = 0; j < 7; j++) {
        float v = fa * Wr[lane * 7 + j] + sa * Wr[(64 + lane) * 7 + j];
        #pragma unroll
        for (int off = 32; off; off >>= 1) v += __shfl_xor(v, off);
        if (lane == j) ps[(size_t)i * 8 + j] = v * di;
    }
}

// Branch-3 gather: 8 nodes per wave, 8 lanes per node (j<7 active on store).
__global__ __launch_bounds__(256) void agg_y_k(const float* __restrict__ ps,
                                               const int* __restrict__ srcidx,
                                               const unsigned* __restrict__ rowptr,
                                               const float* __restrict__ dinv,
                                               const float* __restrict__ br,
                                               float* __restrict__ out_y, int n) {
    int t = blockIdx.x * 256 + threadIdx.x;
    int i = t >> 3, j = t & 7;
    if (i >= n) return;
    unsigned e = rowptr[i], s1 = rowptr[i + 1];
    float acc = ps[(size_t)i * 8 + j];  // self-loop term
    for (; e + 4 <= s1; e += 4) {
        int r0 = srcidx[e], r1 = srcidx[e + 1], r2 = srcidx[e + 2], r3 = srcidx[e + 3];
        acc += (ps[(size_t)r0 * 8 + j] + ps[(size_t)r1 * 8 + j]) +
               (ps[(size_t)r2 * 8 + j] + ps[(size_t)r3 * 8 + j]);
    }
    for (; e < s1; e++) acc += ps[(size_t)srcidx[e] * 8 + j];
    if (j < 7) out_y[(size_t)i * 7 + j] = acc * dinv[i] + br[j];
}

extern "C" void kernel_launch(void* const* d_in, const int* in_sizes, int n_in,
                              void* d_out, int out_size, void* d_ws, size_t ws_size,
                              hipStream_t stream) {
    const float* feature   = (const float*)d_in[0];
    const float* structure = (const float*)d_in[1];
    const void*  ei        = d_in[2];
    const float* Wf  = (const float*)d_in[3];
    const float* bfv = (const float*)d_in[4];
    const float* Ws  = (const float*)d_in[5];
    const float* bs  = (const float*)d_in[6];
    const float* Wr  = (const float*)d_in[7];
    const float* br  = (const float*)d_in[8];
    const float* emb = (const float*)d_in[9];
    const float* embW = (const float*)d_in[10];
    const float* alpha_s = (const float*)d_in[11];
    const float* alpha_a = (const float*)d_in[12];

    const int N = in_sizes[0] / 512;
    const int E = in_sizes[2] / 2;
    const int NB = (N + 255) / 256;

    float* ws = (float*)d_ws;
    size_t XS     = 0;                    // N*64
    size_t SS6    = XS + (size_t)N * 64;  // N*8
    size_t PS     = SS6 + (size_t)N * 8;  // N*8
    size_t DINV   = PS + (size_t)N * 8;   // N
    size_t DEG    = DINV + N;             // N (u32)
    size_t CURSOR = DEG + N;              // N (u32)
    size_t CW     = CURSOR + N;           // 16
    size_t ROWPTR = CW + 16;              // N+1 (u32)
    size_t PART   = ROWPTR + N + 1;       // 1024 (u32)
    size_t WT     = PART + 1024;          // 32768 floats (2x 512*64 ushort)
    size_t SRC    = WT + 32768;           // E (int)

    float* xs = ws + XS;
    float* ss6 = ws + SS6;
    float* ps = ws + PS;
    float* dinv = ws + DINV;
    unsigned* deg = (unsigned*)(ws + DEG);
    unsigned* cursor = (unsigned*)(ws + CURSOR);
    float* cw = ws + CW;
    unsigned* rowptr = (unsigned*)(ws + ROWPTR);
    unsigned* part = (unsigned*)(ws + PART);
    unsigned short* WthG = (unsigned short*)(ws + WT);
    unsigned short* WtlG = WthG + 512 * 64;
    int* srcidx = (int*)(ws + SRC);

    // zero deg + cursor + cw (flag) every call (ws is not re-poisoned between replays)
    hipMemsetAsync(deg, 0, ((size_t)2 * N + 16) * 4, stream);
    detect_k<<<(E + 255) / 256, 256, 0, stream>>>((const int*)ei, (int*)(cw + 8), E);
    setup_k<<<1, 64, 0, stream>>>(emb, embW, alpha_s, alpha_a, cw);
    deg_k<<<(E + 255) / 256, 256, 0, stream>>>(ei, cw, deg, E);
    dinv_k<<<NB, 256, 0, stream>>>(deg, dinv, N);
    scan1_k<<<NB, 256, 0, stream>>>(deg, rowptr, part, N);
    scan2_k<<<1, 64, 0, stream>>>(part, NB);
    scan3_k<<<NB, 256, 0, stream>>>(rowptr, part, N, E);
    fill_k<<<(E + 255) / 256, 256, 0, stream>>>(ei, cw, rowptr, cursor, srcidx, E);
    prep_w_k<<<(512 * 64 + 255) / 256, 256, 0, stream>>>(Wf, WthG, WtlG);
    gemm_f_mfma<<<(N + 127) / 128, 256, 0, stream>>>(feature, WthG, WtlG, dinv, xs, N);
    ss6_k<<<((size_t)N * 8 + 255) / 256, 256, 0, stream>>>(structure, dinv, cw, ss6, N);

    float* out_hf = (float*)d_out;
    float* out_hs = out_hf + (size_t)N * 64;
    float* out_y  = out_hf + (size_t)N * 128;
    agg_fs_k<<<(N + 3) / 4, 256, 0, stream>>>(xs, ss6, srcidx, rowptr, dinv, cw,
                                              bfv, Ws, bs, Wr, out_hf, out_hs, ps, N);
    agg_y_k<<<((size_t)N * 8 + 255) / 256, 256, 0, stream>>>(ps, srcidx, rowptr, dinv,
                                                             br, out_y, N);
}

// Round 5
// 406.464 us; speedup vs baseline: 3.7124x; 1.7361x over previous
//
#include <hip/hip_runtime.h>
#include <hip/hip_bf16.h>

// MORAL: 3x GCNConv, N=100000, E=1.6M, fp32 I/O.
// CSR-by-destination built on device (deg -> scan -> fill), then gather-based
// aggregation (no atomics in hot loops). Pre-scaling by dinv[r] folds the edge
// norm into operands: out[c] = (sum_{r in in(c)} x[r]*dinv[r] + x[c]*dinv[c]) * dinv[c].
// Branch1 GEMM: split-bf16 MFMA. xs stored bf16 to halve gather traffic.
// edge_index dtype (int32 vs int64) detected by sampling odd words (int64 with
// values < 2^31 has zero high-words); counters in R4 proved the harness passes int32.

typedef __attribute__((ext_vector_type(8))) short bf16x8;
typedef __attribute__((ext_vector_type(4))) float f32x4;

__device__ __forceinline__ unsigned short f2bf(float x) {
    union { __hip_bfloat16 b; unsigned short u; } cv;
    cv.b = __float2bfloat16(x);
    return cv.u;
}
__device__ __forceinline__ float bf2f(unsigned short u) {
    union { unsigned u32; float f; } cv;
    cv.u32 = ((unsigned)u) << 16;
    return cv.f;
}

// Sampled dtype detect: 8192 odd-word probes over the first half of the buffer
// (valid addresses under both interpretations). One block; <=4 atomics.
__global__ void detect_k(const int* __restrict__ ei32, int* __restrict__ flag, int E) {
    int t = threadIdx.x;
    bool nz = false;
    #pragma unroll
    for (int s = 0; s < 32; s++) {
        long long idx = ((long long)(s * 256 + t) * (long long)E) >> 13;  // [0,E)
        nz |= (ei32[2 * idx + 1] != 0);
    }
    if (__any(nz) && (t & 63) == 0) atomicOr(flag, 1);
}

__global__ void setup_k(const float* __restrict__ emb,
                        const float* __restrict__ embW,
                        const float* __restrict__ alpha_s,
                        const float* __restrict__ alpha_a,
                        float* __restrict__ cw) {
    int lane = threadIdx.x;  // 64 threads
    float w = embW[lane];
    #pragma unroll
    for (int k = 0; k < 6; k++) {
        float p = emb[k * 64 + lane] * w;
        #pragma unroll
        for (int off = 32; off; off >>= 1) p += __shfl_xor(p, off);
        if (lane == 0) cw[k] = (p < 0.0f) ? 0.0f : 1.0f;  // sigmoid(p)<0.5 <=> p<0
    }
    if (lane == 0) {
        float s = alpha_s[0];
        float a = alpha_a[0];
        float inv = 1.0f / (fabsf(s) + fabsf(a));
        cw[6] = 2.0f * a * inv;  // scale on attr (h_f)
        cw[7] = 2.0f * s * inv;  // scale on struc (h_s)
    }
}

__device__ __forceinline__ void load_edge(const void* ei, int e, int E, int flag,
                                          int& r, int& c) {
    if (flag) {
        const int* p = (const int*)ei;
        r = p[e]; c = p[E + e];
    } else {
        const long long* p = (const long long*)ei;
        r = (int)p[e]; c = (int)p[(size_t)E + e];
    }
}

__global__ void deg_k(const void* __restrict__ ei, const float* __restrict__ cw,
                      unsigned* __restrict__ deg, int E) {
    int e = blockIdx.x * 256 + threadIdx.x;
    if (e >= E) return;
    int flag = ((const int*)cw)[8];
    int c = flag ? ((const int*)ei)[E + e]
                 : (int)((const long long*)ei)[(size_t)E + e];
    atomicAdd(&deg[c], 1u);
}

__global__ void dinv_k(const unsigned* __restrict__ deg, float* __restrict__ dinv, int n) {
    int i = blockIdx.x * 256 + threadIdx.x;
    if (i < n) dinv[i] = rsqrtf((float)deg[i] + 1.0f);  // +1 = self-loop
}

// ---- CSR build: block-local exclusive scan + block totals ----
__global__ __launch_bounds__(256) void scan1_k(const unsigned* __restrict__ deg,
                                               unsigned* __restrict__ rowptr,
                                               unsigned* __restrict__ part, int n) {
    __shared__ unsigned s[256];
    int i = blockIdx.x * 256 + threadIdx.x;
    unsigned v = (i < n) ? deg[i] : 0u;
    s[threadIdx.x] = v;
    __syncthreads();
    #pragma unroll
    for (int off = 1; off < 256; off <<= 1) {
        unsigned t = (threadIdx.x >= off) ? s[threadIdx.x - off] : 0u;
        __syncthreads();
        s[threadIdx.x] += t;
        __syncthreads();
    }
    if (i < n) rowptr[i] = s[threadIdx.x] - v;  // local exclusive
    if (threadIdx.x == 255) part[blockIdx.x] = s[255];
}

__global__ void scan2_k(unsigned* __restrict__ part, int nb) {
    int lane = threadIdx.x;  // 64
    unsigned run = 0;
    for (int base = 0; base < nb; base += 64) {
        unsigned v = (base + lane < nb) ? part[base + lane] : 0u;
        unsigned orig = v;
        #pragma unroll
        for (int off = 1; off < 64; off <<= 1) {
            unsigned t = __shfl_up(v, off);
            if (lane >= off) v += t;
        }
        if (base + lane < nb) part[base + lane] = run + v - orig;
        run += __shfl(v, 63);
    }
}

__global__ void scan3_k(unsigned* __restrict__ rowptr, const unsigned* __restrict__ part,
                        int n, int E) {
    int i = blockIdx.x * 256 + threadIdx.x;
    if (i < n) rowptr[i] += part[blockIdx.x];
    if (i == 0) rowptr[n] = (unsigned)E;
}

__global__ void fill_k(const void* __restrict__ ei, const float* __restrict__ cw,
                       const unsigned* __restrict__ rowptr, unsigned* __restrict__ cursor,
                       int* __restrict__ srcidx, int E) {
    int e = blockIdx.x * 256 + threadIdx.x;
    if (e >= E) return;
    int flag = ((const int*)cw)[8];
    int r, c;
    load_edge(ei, e, E, flag, r, c);
    unsigned pos = atomicAdd(&cursor[c], 1u);
    srcidx[rowptr[c] + pos] = r;
}

// Split+transpose W_f once: Wth/Wtl[c][k] bf16 bits, k contiguous.
__global__ void prep_w_k(const float* __restrict__ Wf,
                         unsigned short* __restrict__ WthG,
                         unsigned short* __restrict__ WtlG) {
    int idx = blockIdx.x * 256 + threadIdx.x;
    if (idx >= 512 * 64) return;
    int k = idx >> 6, c = idx & 63;
    float w = Wf[idx];
    unsigned short h = f2bf(w);
    unsigned short l = f2bf(w - bf2f(h));
    WthG[c * 512 + k] = h;
    WtlG[c * 512 + k] = l;
}

// xs = bf16((feature @ W_f) * dinv[row]), via MFMA split-bf16. Block: 128x64, BK=64.
__global__ __launch_bounds__(256) void gemm_f_mfma(const float* __restrict__ feat,
                                                   const unsigned short* __restrict__ WthG,
                                                   const unsigned short* __restrict__ WtlG,
                                                   const float* __restrict__ dinv,
                                                   unsigned short* __restrict__ xs, int n) {
    __shared__ unsigned short Ah[128 * 64];
    __shared__ unsigned short Al[128 * 64];
    __shared__ unsigned short Bh[64 * 64];
    __shared__ unsigned short Bl[64 * 64];

    const int tid = threadIdx.x;
    const int blk = blockIdx.x;
    const int w = tid >> 6, l = tid & 63;
    const int lr = l & 15, lg = l >> 4;

    f32x4 acc[2][4];
    #pragma unroll
    for (int m = 0; m < 2; m++)
        #pragma unroll
        for (int nt = 0; nt < 4; nt++) acc[m][nt] = (f32x4)(0.0f);

    const int sr = tid >> 1, shalf = tid & 1;       // A: row, k-half
    const int swc = tid >> 2, swq = tid & 3;        // W: col, quarter
    const int gr_ld = min(blk * 128 + sr, n - 1);
    const float* asrc = feat + (size_t)gr_ld * 512 + shalf * 32;

    for (int k0 = 0; k0 < 512; k0 += 64) {
        {
            const float4* s4 = (const float4*)(asrc + k0);
            int base = sr * 128 + shalf * 64;
            int sw = (sr & 7) << 4;
            #pragma unroll
            for (int g = 0; g < 8; g++) {
                float4 v = s4[g];
                ushort4 h, lo;
                h.x = f2bf(v.x); lo.x = f2bf(v.x - bf2f(h.x));
                h.y = f2bf(v.y); lo.y = f2bf(v.y - bf2f(h.y));
                h.z = f2bf(v.z); lo.z = f2bf(v.z - bf2f(h.z));
                h.w = f2bf(v.w); lo.w = f2bf(v.w - bf2f(h.w));
                int off = (base + g * 8) ^ sw;
                *(ushort4*)((char*)Ah + off) = h;
                *(ushort4*)((char*)Al + off) = lo;
            }
        }
        {
            int sw = (swc & 7) << 4;
            const unsigned short* wh = WthG + swc * 512 + k0;
            const unsigned short* wl = WtlG + swc * 512 + k0;
            #pragma unroll
            for (int s = 0; s < 2; s++) {
                int ko16 = swq * 2 + s;
                uint4 vh = *(const uint4*)(wh + ko16 * 8);
                uint4 vl = *(const uint4*)(wl + ko16 * 8);
                int off = (swc * 128 + ko16 * 16) ^ sw;
                *(uint4*)((char*)Bh + off) = vh;
                *(uint4*)((char*)Bl + off) = vl;
            }
        }
        __syncthreads();
        int swl = (lr & 7) << 4;
        #pragma unroll
        for (int ks = 0; ks < 2; ks++) {
            int koff = ks * 64 + lg * 16;
            int ra = ((w * 32 + lr) * 128 + koff) ^ swl;
            bf16x8 ah0 = *(const bf16x8*)((const char*)Ah + ra);
            bf16x8 al0 = *(const bf16x8*)((const char*)Al + ra);
            bf16x8 ah1 = *(const bf16x8*)((const char*)Ah + ra + 16 * 128);
            bf16x8 al1 = *(const bf16x8*)((const char*)Al + ra + 16 * 128);
            #pragma unroll
            for (int nt = 0; nt < 4; nt++) {
                int cb = ((nt * 16 + lr) * 128 + koff) ^ swl;
                bf16x8 bh = *(const bf16x8*)((const char*)Bh + cb);
                bf16x8 bl = *(const bf16x8*)((const char*)Bl + cb);
                acc[0][nt] = __builtin_amdgcn_mfma_f32_16x16x32_bf16(ah0, bh, acc[0][nt], 0, 0, 0);
                acc[0][nt] = __builtin_amdgcn_mfma_f32_16x16x32_bf16(ah0, bl, acc[0][nt], 0, 0, 0);
                acc[0][nt] = __builtin_amdgcn_mfma_f32_16x16x32_bf16(al0, bh, acc[0][nt], 0, 0, 0);
                acc[1][nt] = __builtin_amdgcn_mfma_f32_16x16x32_bf16(ah1, bh, acc[1][nt], 0, 0, 0);
                acc[1][nt] = __builtin_amdgcn_mfma_f32_16x16x32_bf16(ah1, bl, acc[1][nt], 0, 0, 0);
                acc[1][nt] = __builtin_amdgcn_mfma_f32_16x16x32_bf16(al1, bh, acc[1][nt], 0, 0, 0);
            }
        }
        __syncthreads();
    }
    // C/D layout: col=lane&15, row=(lane>>4)*4+reg (m89). Scale by dinv[row], round bf16.
    #pragma unroll
    for (int m = 0; m < 2; m++) {
        int row0 = blk * 128 + w * 32 + m * 16 + lg * 4;
        #pragma unroll
        for (int reg = 0; reg < 4; reg++) {
            int gr = row0 + reg;
            if (gr < n) {
                float dv = dinv[gr];
                #pragma unroll
                for (int nt = 0; nt < 4; nt++)
                    xs[(size_t)gr * 64 + nt * 16 + lr] = f2bf(acc[m][nt][reg] * dv);
            }
        }
    }
}

// ss6[i][k] = structure[i][k] * gate[k] * dinv[i]  (padded stride 8)
__global__ void ss6_k(const float* __restrict__ structure, const float* __restrict__ dinv,
                      const float* __restrict__ cw, float* __restrict__ ss6, int n) {
    int idx = blockIdx.x * 256 + threadIdx.x;
    if (idx >= n * 8) return;
    int i = idx >> 3, k = idx & 7;
    float v = (k < 6) ? structure[i * 6 + k] * cw[k] * dinv[i] : 0.0f;
    ss6[idx] = v;
}

// Gather-aggregate branches 1&2 + fused epilogue: h_f, h_s outputs and
// ps[i][j] = (x @ W_r)[i][j] * dinv[i] for branch 3.
__global__ __launch_bounds__(256) void agg_fs_k(const unsigned short* __restrict__ xs,
                                                const float* __restrict__ ss6,
                                                const int* __restrict__ srcidx,
                                                const unsigned* __restrict__ rowptr,
                                                const float* __restrict__ dinv,
                                                const float* __restrict__ cw,
                                                const float* __restrict__ bfv,
                                                const float* __restrict__ Ws,
                                                const float* __restrict__ bs,
                                                const float* __restrict__ Wr,
                                                float* __restrict__ out_hf,
                                                float* __restrict__ out_hs,
                                                float* __restrict__ ps, int n) {
    int i = blockIdx.x * 4 + (threadIdx.x >> 6);
    int lane = threadIdx.x & 63;
    if (i >= n) return;
    unsigned e = rowptr[i], s1 = rowptr[i + 1];
    float acc = bf2f(xs[(size_t)i * 64 + lane]);    // self-loop term
    float a6 = (lane < 6) ? ss6[i * 8 + lane] : 0.0f;
    for (; e + 4 <= s1; e += 4) {
        int r0 = srcidx[e], r1 = srcidx[e + 1], r2 = srcidx[e + 2], r3 = srcidx[e + 3];
        float v0 = bf2f(xs[(size_t)r0 * 64 + lane]);
        float v1 = bf2f(xs[(size_t)r1 * 64 + lane]);
        float v2 = bf2f(xs[(size_t)r2 * 64 + lane]);
        float v3 = bf2f(xs[(size_t)r3 * 64 + lane]);
        acc += (v0 + v1) + (v2 + v3);
        if (lane < 6)
            a6 += (ss6[r0 * 8 + lane] + ss6[r1 * 8 + lane]) +
                  (ss6[r2 * 8 + lane] + ss6[r3 * 8 + lane]);
    }
    for (; e < s1; e++) {
        int r = srcidx[e];
        acc += bf2f(xs[(size_t)r * 64 + lane]);
        if (lane < 6) a6 += ss6[r * 8 + lane];
    }
    float di = dinv[i];
    float hf = acc * di + bfv[lane];
    float hs = bs[lane];
    #pragma unroll
    for (int k = 0; k < 6; k++) hs += __shfl(a6, k) * di * Ws[k * 64 + lane];
    out_hf[(size_t)i * 64 + lane] = hf;
    out_hs[(size_t)i * 64 + lane] = hs;

    float fa = hf * cw[6];  // attr * a_a * 2
    float sa = hs * cw[7];  // struc * a_s * 2
    #pragma unroll
    for (int j = 0; j < 7; j++) {
        float v = fa * Wr[lane * 7 + j] + sa * Wr[(64 + lane) * 7 + j];
        #pragma unroll
        for (int off = 32; off; off >>= 1) v += __shfl_xor(v, off);
        if (lane == j) ps[(size_t)i * 8 + j] = v * di;
    }
}

// Branch-3 gather: 8 nodes per wave, 8 lanes per node (j<7 active on store).
__global__ __launch_bounds__(256) void agg_y_k(const float* __restrict__ ps,
                                               const int* __restrict__ srcidx,
                                               const unsigned* __restrict__ rowptr,
                                               const float* __restrict__ dinv,
                                               const float* __restrict__ br,
                                               float* __restrict__ out_y, int n) {
    int t = blockIdx.x * 256 + threadIdx.x;
    int i = t >> 3, j = t & 7;
    if (i >= n) return;
    unsigned e = rowptr[i], s1 = rowptr[i + 1];
    float acc = ps[(size_t)i * 8 + j];  // self-loop term
    for (; e + 4 <= s1; e += 4) {
        int r0 = srcidx[e], r1 = srcidx[e + 1], r2 = srcidx[e + 2], r3 = srcidx[e + 3];
        acc += (ps[(size_t)r0 * 8 + j] + ps[(size_t)r1 * 8 + j]) +
               (ps[(size_t)r2 * 8 + j] + ps[(size_t)r3 * 8 + j]);
    }
    for (; e < s1; e++) acc += ps[(size_t)srcidx[e] * 8 + j];
    if (j < 7) out_y[(size_t)i * 7 + j] = acc * dinv[i] + br[j];
}

extern "C" void kernel_launch(void* const* d_in, const int* in_sizes, int n_in,
                              void* d_out, int out_size, void* d_ws, size_t ws_size,
                              hipStream_t stream) {
    const float* feature   = (const float*)d_in[0];
    const float* structure = (const float*)d_in[1];
    const void*  ei        = d_in[2];
    const float* Wf  = (const float*)d_in[3];
    const float* bfv = (const float*)d_in[4];
    const float* Ws  = (const float*)d_in[5];
    const float* bs  = (const float*)d_in[6];
    const float* Wr  = (const float*)d_in[7];
    const float* br  = (const float*)d_in[8];
    const float* emb = (const float*)d_in[9];
    const float* embW = (const float*)d_in[10];
    const float* alpha_s = (const float*)d_in[11];
    const float* alpha_a = (const float*)d_in[12];

    const int N = in_sizes[0] / 512;
    const int E = in_sizes[2] / 2;
    const int NB = (N + 255) / 256;

    float* ws = (float*)d_ws;
    size_t XS     = 0;                    // N*64 ushort = N*32 floats
    size_t SS6    = XS + (size_t)N * 32;  // N*8
    size_t PS     = SS6 + (size_t)N * 8;  // N*8
    size_t DINV   = PS + (size_t)N * 8;   // N
    size_t DEG    = DINV + N;             // N (u32)
    size_t CURSOR = DEG + N;              // N (u32)
    size_t CW     = CURSOR + N;           // 16
    size_t ROWPTR = CW + 16;              // N+1 (u32)
    size_t PART   = ROWPTR + N + 1;       // 1024 (u32)
    size_t WT     = PART + 1024;          // 32768 floats (2x 512*64 ushort)
    size_t SRC    = WT + 32768;           // E (int)

    unsigned short* xs = (unsigned short*)(ws + XS);
    float* ss6 = ws + SS6;
    float* ps = ws + PS;
    float* dinv = ws + DINV;
    unsigned* deg = (unsigned*)(ws + DEG);
    unsigned* cursor = (unsigned*)(ws + CURSOR);
    float* cw = ws + CW;
    unsigned* rowptr = (unsigned*)(ws + ROWPTR);
    unsigned* part = (unsigned*)(ws + PART);
    unsigned short* WthG = (unsigned short*)(ws + WT);
    unsigned short* WtlG = WthG + 512 * 64;
    int* srcidx = (int*)(ws + SRC);

    // zero deg + cursor + cw (flag) every call (ws is not re-poisoned between replays)
    hipMemsetAsync(deg, 0, ((size_t)2 * N + 16) * 4, stream);
    detect_k<<<1, 256, 0, stream>>>((const int*)ei, (int*)(cw + 8), E);
    setup_k<<<1, 64, 0, stream>>>(emb, embW, alpha_s, alpha_a, cw);
    deg_k<<<(E + 255) / 256, 256, 0, stream>>>(ei, cw, deg, E);
    dinv_k<<<NB, 256, 0, stream>>>(deg, dinv, N);
    scan1_k<<<NB, 256, 0, stream>>>(deg, rowptr, part, N);
    scan2_k<<<1, 64, 0, stream>>>(part, NB);
    scan3_k<<<NB, 256, 0, stream>>>(rowptr, part, N, E);
    fill_k<<<(E + 255) / 256, 256, 0, stream>>>(ei, cw, rowptr, cursor, srcidx, E);
    prep_w_k<<<(512 * 64 + 255) / 256, 256, 0, stream>>>(Wf, WthG, WtlG);
    gemm_f_mfma<<<(N + 127) / 128, 256, 0, stream>>>(feature, WthG, WtlG, dinv, xs, N);
    ss6_k<<<((size_t)N * 8 + 255) / 256, 256, 0, stream>>>(structure, dinv, cw, ss6, N);

    float* out_hf = (float*)d_out;
    float* out_hs = out_hf + (size_t)N * 64;
    float* out_y  = out_hf + (size_t)N * 128;
    agg_fs_k<<<(N + 3) / 4, 256, 0, stream>>>(xs, ss6, srcidx, rowptr, dinv, cw,
                                              bfv, Ws, bs, Wr, out_hf, out_hs, ps, N);
    agg_y_k<<<((size_t)N * 8 + 255) / 256, 256, 0, stream>>>(ps, srcidx, rowptr, dinv,
                                                             br, out_y, N);
}

// Round 6
// 400.114 us; speedup vs baseline: 3.7713x; 1.0159x over previous
//
#include <hip/hip_runtime.h>
#include <hip/hip_bf16.h>

// MORAL: 3x GCNConv, N=100000, E=1.6M, fp32 I/O.
// CSR-by-dest on device, gather-based aggregation (no hot atomics).
// agg kernels: per-node srcidx list loaded up-front by lanes, indices
// distributed via shfl -> gathers issue 8+ deep (latency hiding).
// Branch1 GEMM: A bf16, B split hi/lo (2-term MFMA). xs stored bf16.

typedef __attribute__((ext_vector_type(8))) short bf16x8;
typedef __attribute__((ext_vector_type(4))) float f32x4;

__device__ __forceinline__ unsigned short f2bf(float x) {
    union { __hip_bfloat16 b; unsigned short u; } cv;
    cv.b = __float2bfloat16(x);
    return cv.u;
}
__device__ __forceinline__ float bf2f(unsigned short u) {
    union { unsigned u32; float f; } cv;
    cv.u32 = ((unsigned)u) << 16;
    return cv.f;
}

// Sampled dtype detect: 8192 odd-word probes (int64 with values < 2^31 has
// zero high words). R4 counters proved harness passes int32.
__global__ void detect_k(const int* __restrict__ ei32, int* __restrict__ flag, int E) {
    int t = threadIdx.x;
    bool nz = false;
    #pragma unroll
    for (int s = 0; s < 32; s++) {
        long long idx = ((long long)(s * 256 + t) * (long long)E) >> 13;  // [0,E)
        nz |= (ei32[2 * idx + 1] != 0);
    }
    if (__any(nz) && (t & 63) == 0) atomicOr(flag, 1);
}

__global__ void setup_k(const float* __restrict__ emb,
                        const float* __restrict__ embW,
                        const float* __restrict__ alpha_s,
                        const float* __restrict__ alpha_a,
                        float* __restrict__ cw) {
    int lane = threadIdx.x;  // 64 threads
    float w = embW[lane];
    #pragma unroll
    for (int k = 0; k < 6; k++) {
        float p = emb[k * 64 + lane] * w;
        #pragma unroll
        for (int off = 32; off; off >>= 1) p += __shfl_xor(p, off);
        if (lane == 0) cw[k] = (p < 0.0f) ? 0.0f : 1.0f;  // sigmoid(p)<0.5 <=> p<0
    }
    if (lane == 0) {
        float s = alpha_s[0];
        float a = alpha_a[0];
        float inv = 1.0f / (fabsf(s) + fabsf(a));
        cw[6] = 2.0f * a * inv;  // scale on attr (h_f)
        cw[7] = 2.0f * s * inv;  // scale on struc (h_s)
    }
}

__device__ __forceinline__ void load_edge(const void* ei, int e, int E, int flag,
                                          int& r, int& c) {
    if (flag) {
        const int* p = (const int*)ei;
        r = p[e]; c = p[E + e];
    } else {
        const long long* p = (const long long*)ei;
        r = (int)p[e]; c = (int)p[(size_t)E + e];
    }
}

__global__ void deg_k(const void* __restrict__ ei, const float* __restrict__ cw,
                      unsigned* __restrict__ deg, int E) {
    int e = blockIdx.x * 256 + threadIdx.x;
    if (e >= E) return;
    int flag = ((const int*)cw)[8];
    int c = flag ? ((const int*)ei)[E + e]
                 : (int)((const long long*)ei)[(size_t)E + e];
    atomicAdd(&deg[c], 1u);
}

// ---- CSR build + fused dinv/ss6 ----
__global__ __launch_bounds__(256) void scan1_k(const unsigned* __restrict__ deg,
                                               unsigned* __restrict__ rowptr,
                                               unsigned* __restrict__ part,
                                               float* __restrict__ dinv,
                                               const float* __restrict__ structure,
                                               const float* __restrict__ cw,
                                               float* __restrict__ ss6, int n) {
    __shared__ unsigned s[256];
    int i = blockIdx.x * 256 + threadIdx.x;
    unsigned v = (i < n) ? deg[i] : 0u;
    if (i < n) {
        float dv = rsqrtf((float)v + 1.0f);  // +1 = self-loop
        dinv[i] = dv;
        #pragma unroll
        for (int k = 0; k < 6; k++) ss6[i * 8 + k] = structure[i * 6 + k] * cw[k] * dv;
        ss6[i * 8 + 6] = 0.0f;
        ss6[i * 8 + 7] = 0.0f;
    }
    s[threadIdx.x] = v;
    __syncthreads();
    #pragma unroll
    for (int off = 1; off < 256; off <<= 1) {
        unsigned t = (threadIdx.x >= off) ? s[threadIdx.x - off] : 0u;
        __syncthreads();
        s[threadIdx.x] += t;
        __syncthreads();
    }
    if (i < n) rowptr[i] = s[threadIdx.x] - v;  // local exclusive
    if (threadIdx.x == 255) part[blockIdx.x] = s[255];
}

__global__ void scan2_k(unsigned* __restrict__ part, int nb) {
    int lane = threadIdx.x;  // 64
    unsigned run = 0;
    for (int base = 0; base < nb; base += 64) {
        unsigned v = (base + lane < nb) ? part[base + lane] : 0u;
        unsigned orig = v;
        #pragma unroll
        for (int off = 1; off < 64; off <<= 1) {
            unsigned t = __shfl_up(v, off);
            if (lane >= off) v += t;
        }
        if (base + lane < nb) part[base + lane] = run + v - orig;
        run += __shfl(v, 63);
    }
}

__global__ void scan3_k(unsigned* __restrict__ rowptr, const unsigned* __restrict__ part,
                        int n, int E) {
    int i = blockIdx.x * 256 + threadIdx.x;
    if (i < n) rowptr[i] += part[blockIdx.x];
    if (i == 0) rowptr[n] = (unsigned)E;
}

__global__ void fill_k(const void* __restrict__ ei, const float* __restrict__ cw,
                       const unsigned* __restrict__ rowptr, unsigned* __restrict__ cursor,
                       int* __restrict__ srcidx, int E) {
    int e = blockIdx.x * 256 + threadIdx.x;
    if (e >= E) return;
    int flag = ((const int*)cw)[8];
    int r, c;
    load_edge(ei, e, E, flag, r, c);
    unsigned pos = atomicAdd(&cursor[c], 1u);
    srcidx[rowptr[c] + pos] = r;
}

// Split+transpose W_f once: Wth/Wtl[c][k] bf16 bits, k contiguous.
__global__ void prep_w_k(const float* __restrict__ Wf,
                         unsigned short* __restrict__ WthG,
                         unsigned short* __restrict__ WtlG) {
    int idx = blockIdx.x * 256 + threadIdx.x;
    if (idx >= 512 * 64) return;
    int k = idx >> 6, c = idx & 63;
    float w = Wf[idx];
    unsigned short h = f2bf(w);
    unsigned short l = f2bf(w - bf2f(h));
    WthG[c * 512 + k] = h;
    WtlG[c * 512 + k] = l;
}

// xs = bf16((feature @ W_f) * dinv[row]): A bf16, B split (Ah*Bh + Ah*Bl).
__global__ __launch_bounds__(256) void gemm_f_mfma(const float* __restrict__ feat,
                                                   const unsigned short* __restrict__ WthG,
                                                   const unsigned short* __restrict__ WtlG,
                                                   const float* __restrict__ dinv,
                                                   unsigned short* __restrict__ xs, int n) {
    __shared__ unsigned short Ah[128 * 64];
    __shared__ unsigned short Bh[64 * 64];
    __shared__ unsigned short Bl[64 * 64];

    const int tid = threadIdx.x;
    const int blk = blockIdx.x;
    const int w = tid >> 6, l = tid & 63;
    const int lr = l & 15, lg = l >> 4;

    f32x4 acc[2][4];
    #pragma unroll
    for (int m = 0; m < 2; m++)
        #pragma unroll
        for (int nt = 0; nt < 4; nt++) acc[m][nt] = (f32x4)(0.0f);

    const int sr = tid >> 1, shalf = tid & 1;       // A: row, k-half
    const int swc = tid >> 2, swq = tid & 3;        // W: col, quarter
    const int gr_ld = min(blk * 128 + sr, n - 1);
    const float* asrc = feat + (size_t)gr_ld * 512 + shalf * 32;

    for (int k0 = 0; k0 < 512; k0 += 64) {
        {
            const float4* s4 = (const float4*)(asrc + k0);
            int base = sr * 128 + shalf * 64;
            int sw = (sr & 7) << 4;
            #pragma unroll
            for (int g = 0; g < 8; g++) {
                float4 v = s4[g];
                ushort4 h;
                h.x = f2bf(v.x); h.y = f2bf(v.y); h.z = f2bf(v.z); h.w = f2bf(v.w);
                *(ushort4*)((char*)Ah + ((base + g * 8) ^ sw)) = h;
            }
        }
        {
            int sw = (swc & 7) << 4;
            const unsigned short* wh = WthG + swc * 512 + k0;
            const unsigned short* wl = WtlG + swc * 512 + k0;
            #pragma unroll
            for (int s = 0; s < 2; s++) {
                int ko16 = swq * 2 + s;
                uint4 vh = *(const uint4*)(wh + ko16 * 8);
                uint4 vl = *(const uint4*)(wl + ko16 * 8);
                int off = (swc * 128 + ko16 * 16) ^ sw;
                *(uint4*)((char*)Bh + off) = vh;
                *(uint4*)((char*)Bl + off) = vl;
            }
        }
        __syncthreads();
        int swl = (lr & 7) << 4;
        #pragma unroll
        for (int ks = 0; ks < 2; ks++) {
            int koff = ks * 64 + lg * 16;
            int ra = ((w * 32 + lr) * 128 + koff) ^ swl;
            bf16x8 ah0 = *(const bf16x8*)((const char*)Ah + ra);
            bf16x8 ah1 = *(const bf16x8*)((const char*)Ah + ra + 16 * 128);
            #pragma unroll
            for (int nt = 0; nt < 4; nt++) {
                int cb = ((nt * 16 + lr) * 128 + koff) ^ swl;
                bf16x8 bh = *(const bf16x8*)((const char*)Bh + cb);
                bf16x8 bl = *(const bf16x8*)((const char*)Bl + cb);
                acc[0][nt] = __builtin_amdgcn_mfma_f32_16x16x32_bf16(ah0, bh, acc[0][nt], 0, 0, 0);
                acc[0][nt] = __builtin_amdgcn_mfma_f32_16x16x32_bf16(ah0, bl, acc[0][nt], 0, 0, 0);
                acc[1][nt] = __builtin_amdgcn_mfma_f32_16x16x32_bf16(ah1, bh, acc[1][nt], 0, 0, 0);
                acc[1][nt] = __builtin_amdgcn_mfma_f32_16x16x32_bf16(ah1, bl, acc[1][nt], 0, 0, 0);
            }
        }
        __syncthreads();
    }
    // C/D layout: col=lane&15, row=(lane>>4)*4+reg (m89). Scale by dinv, round bf16.
    #pragma unroll
    for (int m = 0; m < 2; m++) {
        int row0 = blk * 128 + w * 32 + m * 16 + lg * 4;
        #pragma unroll
        for (int reg = 0; reg < 4; reg++) {
            int gr = row0 + reg;
            if (gr < n) {
                float dv = dinv[gr];
                #pragma unroll
                for (int nt = 0; nt < 4; nt++)
                    xs[(size_t)gr * 64 + nt * 16 + lr] = f2bf(acc[m][nt][reg] * dv);
            }
        }
    }
}

// Gather-aggregate branches 1&2 + fused epilogue. Wave per node: srcidx list
// loaded up-front by lanes, distributed via shfl; gathers 8-deep independent.
__global__ __launch_bounds__(256) void agg_fs_k(const unsigned short* __restrict__ xs,
                                                const float* __restrict__ ss6,
                                                const int* __restrict__ srcidx,
                                                const unsigned* __restrict__ rowptr,
                                                const float* __restrict__ dinv,
                                                const float* __restrict__ cw,
                                                const float* __restrict__ bfv,
                                                const float* __restrict__ Ws,
                                                const float* __restrict__ bs,
                                                const float* __restrict__ Wr,
                                                float* __restrict__ out_hf,
                                                float* __restrict__ out_hs,
                                                float* __restrict__ ps, int n) {
    int i = blockIdx.x * 4 + (threadIdx.x >> 6);
    int lane = threadIdx.x & 63;
    if (i >= n) return;
    unsigned e0 = rowptr[i];
    int deg = (int)(rowptr[i + 1] - e0);
    float acc = bf2f(xs[(size_t)i * 64 + lane]);    // self-loop term
    float a6 = (lane < 6) ? ss6[i * 8 + lane] : 0.0f;

    for (int base = 0; base < deg; base += 64) {
        int cnt = min(deg - base, 64);
        int rl = (lane < cnt) ? srcidx[e0 + base + lane] : 0;
        int d = 0;
        for (; d + 8 <= cnt; d += 8) {
            int r0 = __shfl(rl, d + 0), r1 = __shfl(rl, d + 1);
            int r2 = __shfl(rl, d + 2), r3 = __shfl(rl, d + 3);
            int r4 = __shfl(rl, d + 4), r5 = __shfl(rl, d + 5);
            int r6 = __shfl(rl, d + 6), r7 = __shfl(rl, d + 7);
            float v0 = bf2f(xs[(size_t)r0 * 64 + lane]);
            float v1 = bf2f(xs[(size_t)r1 * 64 + lane]);
            float v2 = bf2f(xs[(size_t)r2 * 64 + lane]);
            float v3 = bf2f(xs[(size_t)r3 * 64 + lane]);
            float v4 = bf2f(xs[(size_t)r4 * 64 + lane]);
            float v5 = bf2f(xs[(size_t)r5 * 64 + lane]);
            float v6 = bf2f(xs[(size_t)r6 * 64 + lane]);
            float v7 = bf2f(xs[(size_t)r7 * 64 + lane]);
            acc += ((v0 + v1) + (v2 + v3)) + ((v4 + v5) + (v6 + v7));
            if (lane < 6) {
                float u0 = ss6[r0 * 8 + lane], u1 = ss6[r1 * 8 + lane];
                float u2 = ss6[r2 * 8 + lane], u3 = ss6[r3 * 8 + lane];
                float u4 = ss6[r4 * 8 + lane], u5 = ss6[r5 * 8 + lane];
                float u6 = ss6[r6 * 8 + lane], u7 = ss6[r7 * 8 + lane];
                a6 += ((u0 + u1) + (u2 + u3)) + ((u4 + u5) + (u6 + u7));
            }
        }
        for (; d < cnt; d++) {
            int r = __shfl(rl, d);
            acc += bf2f(xs[(size_t)r * 64 + lane]);
            if (lane < 6) a6 += ss6[r * 8 + lane];
        }
    }
    float di = dinv[i];
    float hf = acc * di + bfv[lane];
    float hs = bs[lane];
    #pragma unroll
    for (int k = 0; k < 6; k++) hs += __shfl(a6, k) * di * Ws[k * 64 + lane];
    out_hf[(size_t)i * 64 + lane] = hf;
    out_hs[(size_t)i * 64 + lane] = hs;

    float fa = hf * cw[6];  // attr * a_a * 2
    float sa = hs * cw[7];  // struc * a_s * 2
    #pragma unroll
    for (int j = 0; j < 7; j++) {
        float v = fa * Wr[lane * 7 + j] + sa * Wr[(64 + lane) * 7 + j];
        #pragma unroll
        for (int off = 32; off; off >>= 1) v += __shfl_xor(v, off);
        if (lane == j) ps[(size_t)i * 8 + j] = v * di;
    }
    if (lane == 7) ps[(size_t)i * 8 + 7] = 0.0f;
}

// Branch-3 gather: wave per node, 8 edge-slots x 8 dims; reduce via shfl_xor.
__global__ __launch_bounds__(256) void agg_y_k(const float* __restrict__ ps,
                                               const int* __restrict__ srcidx,
                                               const unsigned* __restrict__ rowptr,
                                               const float* __restrict__ dinv,
                                               const float* __restrict__ br,
                                               float* __restrict__ out_y, int n) {
    int i = blockIdx.x * 4 + (threadIdx.x >> 6);
    int lane = threadIdx.x & 63;
    if (i >= n) return;
    int es = lane >> 3, j = lane & 7;  // edge-slot, dim
    unsigned e0 = rowptr[i];
    int deg = (int)(rowptr[i + 1] - e0);
    float acc = (es == 0) ? ps[(size_t)i * 8 + j] : 0.0f;  // self-loop in slot 0
    int base = 0;
    for (; base + 16 <= deg; base += 16) {
        int ra = srcidx[e0 + base + es];
        int rb = srcidx[e0 + base + 8 + es];
        acc += ps[(size_t)ra * 8 + j] + ps[(size_t)rb * 8 + j];
    }
    for (; base < deg; base += 8) {
        int idx = base + es;
        if (idx < deg) acc += ps[(size_t)srcidx[e0 + idx] * 8 + j];
    }
    acc += __shfl_xor(acc, 8);
    acc += __shfl_xor(acc, 16);
    acc += __shfl_xor(acc, 32);
    if (j < 7) out_y[(size_t)i * 7 + j] = acc * dinv[i] + br[j];
}

extern "C" void kernel_launch(void* const* d_in, const int* in_sizes, int n_in,
                              void* d_out, int out_size, void* d_ws, size_t ws_size,
                              hipStream_t stream) {
    const float* feature   = (const float*)d_in[0];
    const float* structure = (const float*)d_in[1];
    const void*  ei        = d_in[2];
    const float* Wf  = (const float*)d_in[3];
    const float* bfv = (const float*)d_in[4];
    const float* Ws  = (const float*)d_in[5];
    const float* bs  = (const float*)d_in[6];
    const float* Wr  = (const float*)d_in[7];
    const float* br  = (const float*)d_in[8];
    const float* emb = (const float*)d_in[9];
    const float* embW = (const float*)d_in[10];
    const float* alpha_s = (const float*)d_in[11];
    const float* alpha_a = (const float*)d_in[12];

    const int N = in_sizes[0] / 512;
    const int E = in_sizes[2] / 2;
    const int NB = (N + 255) / 256;

    float* ws = (float*)d_ws;
    size_t XS     = 0;                    // N*64 ushort = N*32 floats
    size_t SS6    = XS + (size_t)N * 32;  // N*8
    size_t PS     = SS6 + (size_t)N * 8;  // N*8
    size_t DINV   = PS + (size_t)N * 8;   // N
    size_t DEG    = DINV + N;             // N (u32)
    size_t CURSOR = DEG + N;              // N (u32)
    size_t CW     = CURSOR + N;           // 16
    size_t ROWPTR = CW + 16;              // N+1 (u32)
    size_t PART   = ROWPTR + N + 1;       // 1024 (u32)
    size_t WT     = PART + 1024;          // 32768 floats (2x 512*64 ushort)
    size_t SRC    = WT + 32768;           // E (int)

    unsigned short* xs = (unsigned short*)(ws + XS);
    float* ss6 = ws + SS6;
    float* ps = ws + PS;
    float* dinv = ws + DINV;
    unsigned* deg = (unsigned*)(ws + DEG);
    unsigned* cursor = (unsigned*)(ws + CURSOR);
    float* cw = ws + CW;
    unsigned* rowptr = (unsigned*)(ws + ROWPTR);
    unsigned* part = (unsigned*)(ws + PART);
    unsigned short* WthG = (unsigned short*)(ws + WT);
    unsigned short* WtlG = WthG + 512 * 64;
    int* srcidx = (int*)(ws + SRC);

    // zero deg + cursor + cw (flag) every call (ws is not re-poisoned between replays)
    hipMemsetAsync(deg, 0, ((size_t)2 * N + 16) * 4, stream);
    detect_k<<<1, 256, 0, stream>>>((const int*)ei, (int*)(cw + 8), E);
    setup_k<<<1, 64, 0, stream>>>(emb, embW, alpha_s, alpha_a, cw);
    deg_k<<<(E + 255) / 256, 256, 0, stream>>>(ei, cw, deg, E);
    scan1_k<<<NB, 256, 0, stream>>>(deg, rowptr, part, dinv, structure, cw, ss6, N);
    scan2_k<<<1, 64, 0, stream>>>(part, NB);
    scan3_k<<<NB, 256, 0, stream>>>(rowptr, part, N, E);
    fill_k<<<(E + 255) / 256, 256, 0, stream>>>(ei, cw, rowptr, cursor, srcidx, E);
    prep_w_k<<<(512 * 64 + 255) / 256, 256, 0, stream>>>(Wf, WthG, WtlG);
    gemm_f_mfma<<<(N + 127) / 128, 256, 0, stream>>>(feature, WthG, WtlG, dinv, xs, N);

    float* out_hf = (float*)d_out;
    float* out_hs = out_hf + (size_t)N * 64;
    float* out_y  = out_hf + (size_t)N * 128;
    agg_fs_k<<<(N + 3) / 4, 256, 0, stream>>>(xs, ss6, srcidx, rowptr, dinv, cw,
                                              bfv, Ws, bs, Wr, out_hf, out_hs, ps, N);
    agg_y_k<<<(N + 3) / 4, 256, 0, stream>>>(ps, srcidx, rowptr, dinv, br, out_y, N);
}

// Round 7
// 370.253 us; speedup vs baseline: 4.0754x; 1.0807x over previous
//
#include <hip/hip_runtime.h>
#include <hip/hip_bf16.h>

// MORAL: 3x GCNConv, N=100000, E=1.6M, fp32 I/O.
// CSR-by-dest on device, gather-based aggregation (no hot atomics).
// agg_fs: 2 nodes per wave, 8-deep gather groups per node (16 loads in
// flight). ss6 stored bf16 (1.6MB, XCD-L2-resident). xs bf16 (12.8MB).
// Edge dtype (int32 vs int64) self-detected per wave from odd words.
// Branch1 GEMM: A bf16, B split hi/lo (2-term MFMA).

typedef __attribute__((ext_vector_type(8))) short bf16x8;
typedef __attribute__((ext_vector_type(4))) float f32x4;

__device__ __forceinline__ unsigned short f2bf(float x) {
    union { __hip_bfloat16 b; unsigned short u; } cv;
    cv.b = __float2bfloat16(x);
    return cv.u;
}
__device__ __forceinline__ float bf2f(unsigned short u) {
    union { unsigned u32; float f; } cv;
    cv.u32 = ((unsigned)u) << 16;
    return cv.f;
}

// setup (block 0, wave 0) + W_f split/transpose (blocks 1..128)
__global__ __launch_bounds__(256) void setup_prep_k(const float* __restrict__ emb,
                                                    const float* __restrict__ embW,
                                                    const float* __restrict__ alpha_s,
                                                    const float* __restrict__ alpha_a,
                                                    float* __restrict__ cw,
                                                    const float* __restrict__ Wf,
                                                    unsigned short* __restrict__ WthG,
                                                    unsigned short* __restrict__ WtlG) {
    if (blockIdx.x == 0) {
        if (threadIdx.x >= 64) return;
        int lane = threadIdx.x;
        float w = embW[lane];
        #pragma unroll
        for (int k = 0; k < 6; k++) {
            float p = emb[k * 64 + lane] * w;
            #pragma unroll
            for (int off = 32; off; off >>= 1) p += __shfl_xor(p, off);
            if (lane == 0) cw[k] = (p < 0.0f) ? 0.0f : 1.0f;  // sigmoid(p)<0.5 <=> p<0
        }
        if (lane == 0) {
            float s = alpha_s[0];
            float a = alpha_a[0];
            float inv = 1.0f / (fabsf(s) + fabsf(a));
            cw[6] = 2.0f * a * inv;  // scale on attr (h_f)
            cw[7] = 2.0f * s * inv;  // scale on struc (h_s)
        }
        return;
    }
    int idx = (blockIdx.x - 1) * 256 + threadIdx.x;
    if (idx >= 512 * 64) return;
    int k = idx >> 6, c = idx & 63;
    float w = Wf[idx];
    unsigned short h = f2bf(w);
    unsigned short l = f2bf(w - bf2f(h));
    WthG[c * 512 + k] = h;
    WtlG[c * 512 + k] = l;
}

// Per-wave dtype self-detection: sample 64 odd 32-bit words. int64 (<2^31
// values) -> all zero; int32 random indices -> nonzero (P(all 0)=1e-5^64).
__device__ __forceinline__ bool detect32(const int* p32, int e, int E, int lane) {
    int se = (e < E) ? e : lane;  // E >> 64
    return __any(p32[2 * se + 1] != 0);
}

__global__ void deg_k(const void* __restrict__ ei, unsigned* __restrict__ deg, int E) {
    int e = blockIdx.x * 256 + threadIdx.x;
    int lane = threadIdx.x & 63;
    const int* p32 = (const int*)ei;
    bool is32 = detect32(p32, e, E, lane);
    if (e >= E) return;
    int c = is32 ? p32[E + e] : (int)((const long long*)ei)[(size_t)E + e];
    atomicAdd(&deg[c], 1u);
}

// ---- CSR build + fused dinv/ss6(bf16) ----
__global__ __launch_bounds__(256) void scan1_k(const unsigned* __restrict__ deg,
                                               unsigned* __restrict__ rowptr,
                                               unsigned* __restrict__ part,
                                               float* __restrict__ dinv,
                                               const float* __restrict__ structure,
                                               const float* __restrict__ cw,
                                               unsigned short* __restrict__ ss6, int n) {
    __shared__ unsigned s[256];
    int i = blockIdx.x * 256 + threadIdx.x;
    unsigned v = (i < n) ? deg[i] : 0u;
    if (i < n) {
        float dv = rsqrtf((float)v + 1.0f);  // +1 = self-loop
        dinv[i] = dv;
        #pragma unroll
        for (int k = 0; k < 6; k++) ss6[i * 8 + k] = f2bf(structure[i * 6 + k] * cw[k] * dv);
        ss6[i * 8 + 6] = 0;
        ss6[i * 8 + 7] = 0;
    }
    s[threadIdx.x] = v;
    __syncthreads();
    #pragma unroll
    for (int off = 1; off < 256; off <<= 1) {
        unsigned t = (threadIdx.x >= off) ? s[threadIdx.x - off] : 0u;
        __syncthreads();
        s[threadIdx.x] += t;
        __syncthreads();
    }
    if (i < n) rowptr[i] = s[threadIdx.x] - v;  // local exclusive
    if (threadIdx.x == 255) part[blockIdx.x] = s[255];
}

__global__ void scan2_k(unsigned* __restrict__ part, int nb) {
    int lane = threadIdx.x;  // 64
    unsigned run = 0;
    for (int base = 0; base < nb; base += 64) {
        unsigned v = (base + lane < nb) ? part[base + lane] : 0u;
        unsigned orig = v;
        #pragma unroll
        for (int off = 1; off < 64; off <<= 1) {
            unsigned t = __shfl_up(v, off);
            if (lane >= off) v += t;
        }
        if (base + lane < nb) part[base + lane] = run + v - orig;
        run += __shfl(v, 63);
    }
}

__global__ void scan3_k(unsigned* __restrict__ rowptr, const unsigned* __restrict__ part,
                        int n, int E) {
    int i = blockIdx.x * 256 + threadIdx.x;
    if (i < n) rowptr[i] += part[blockIdx.x];
    if (i == 0) rowptr[n] = (unsigned)E;
}

__global__ void fill_k(const void* __restrict__ ei,
                       const unsigned* __restrict__ rowptr, unsigned* __restrict__ cursor,
                       int* __restrict__ srcidx, int E) {
    int e = blockIdx.x * 256 + threadIdx.x;
    int lane = threadIdx.x & 63;
    const int* p32 = (const int*)ei;
    bool is32 = detect32(p32, e, E, lane);
    if (e >= E) return;
    int r, c;
    if (is32) {
        r = p32[e]; c = p32[E + e];
    } else {
        const long long* p = (const long long*)ei;
        r = (int)p[e]; c = (int)p[(size_t)E + e];
    }
    unsigned pos = atomicAdd(&cursor[c], 1u);
    srcidx[rowptr[c] + pos] = r;
}

// xs = bf16((feature @ W_f) * dinv[row]): A bf16, B split (Ah*Bh + Ah*Bl).
__global__ __launch_bounds__(256) void gemm_f_mfma(const float* __restrict__ feat,
                                                   const unsigned short* __restrict__ WthG,
                                                   const unsigned short* __restrict__ WtlG,
                                                   const float* __restrict__ dinv,
                                                   unsigned short* __restrict__ xs, int n) {
    __shared__ unsigned short Ah[128 * 64];
    __shared__ unsigned short Bh[64 * 64];
    __shared__ unsigned short Bl[64 * 64];

    const int tid = threadIdx.x;
    const int blk = blockIdx.x;
    const int w = tid >> 6, l = tid & 63;
    const int lr = l & 15, lg = l >> 4;

    f32x4 acc[2][4];
    #pragma unroll
    for (int m = 0; m < 2; m++)
        #pragma unroll
        for (int nt = 0; nt < 4; nt++) acc[m][nt] = (f32x4)(0.0f);

    const int sr = tid >> 1, shalf = tid & 1;       // A: row, k-half
    const int swc = tid >> 2, swq = tid & 3;        // W: col, quarter
    const int gr_ld = min(blk * 128 + sr, n - 1);
    const float* asrc = feat + (size_t)gr_ld * 512 + shalf * 32;

    for (int k0 = 0; k0 < 512; k0 += 64) {
        {
            const float4* s4 = (const float4*)(asrc + k0);
            int base = sr * 128 + shalf * 64;
            int sw = (sr & 7) << 4;
            #pragma unroll
            for (int g = 0; g < 8; g++) {
                float4 v = s4[g];
                ushort4 h;
                h.x = f2bf(v.x); h.y = f2bf(v.y); h.z = f2bf(v.z); h.w = f2bf(v.w);
                *(ushort4*)((char*)Ah + ((base + g * 8) ^ sw)) = h;
            }
        }
        {
            int sw = (swc & 7) << 4;
            const unsigned short* wh = WthG + swc * 512 + k0;
            const unsigned short* wl = WtlG + swc * 512 + k0;
            #pragma unroll
            for (int s = 0; s < 2; s++) {
                int ko16 = swq * 2 + s;
                uint4 vh = *(const uint4*)(wh + ko16 * 8);
                uint4 vl = *(const uint4*)(wl + ko16 * 8);
                int off = (swc * 128 + ko16 * 16) ^ sw;
                *(uint4*)((char*)Bh + off) = vh;
                *(uint4*)((char*)Bl + off) = vl;
            }
        }
        __syncthreads();
        int swl = (lr & 7) << 4;
        #pragma unroll
        for (int ks = 0; ks < 2; ks++) {
            int koff = ks * 64 + lg * 16;
            int ra = ((w * 32 + lr) * 128 + koff) ^ swl;
            bf16x8 ah0 = *(const bf16x8*)((const char*)Ah + ra);
            bf16x8 ah1 = *(const bf16x8*)((const char*)Ah + ra + 16 * 128);
            #pragma unroll
            for (int nt = 0; nt < 4; nt++) {
                int cb = ((nt * 16 + lr) * 128 + koff) ^ swl;
                bf16x8 bh = *(const bf16x8*)((const char*)Bh + cb);
                bf16x8 bl = *(const bf16x8*)((const char*)Bl + cb);
                acc[0][nt] = __builtin_amdgcn_mfma_f32_16x16x32_bf16(ah0, bh, acc[0][nt], 0, 0, 0);
                acc[0][nt] = __builtin_amdgcn_mfma_f32_16x16x32_bf16(ah0, bl, acc[0][nt], 0, 0, 0);
                acc[1][nt] = __builtin_amdgcn_mfma_f32_16x16x32_bf16(ah1, bh, acc[1][nt], 0, 0, 0);
                acc[1][nt] = __builtin_amdgcn_mfma_f32_16x16x32_bf16(ah1, bl, acc[1][nt], 0, 0, 0);
            }
        }
        __syncthreads();
    }
    // C/D layout: col=lane&15, row=(lane>>4)*4+reg (m89). Scale by dinv, round bf16.
    #pragma unroll
    for (int m = 0; m < 2; m++) {
        int row0 = blk * 128 + w * 32 + m * 16 + lg * 4;
        #pragma unroll
        for (int reg = 0; reg < 4; reg++) {
            int gr = row0 + reg;
            if (gr < n) {
                float dv = dinv[gr];
                #pragma unroll
                for (int nt = 0; nt < 4; nt++)
                    xs[(size_t)gr * 64 + nt * 16 + lr] = f2bf(acc[m][nt][reg] * dv);
            }
        }
    }
}

#define GATHER8(rl, g, accv, a6v)                                              \
    {                                                                          \
        int r0 = __shfl(rl, g + 0), r1 = __shfl(rl, g + 1);                    \
        int r2 = __shfl(rl, g + 2), r3 = __shfl(rl, g + 3);                    \
        int r4 = __shfl(rl, g + 4), r5 = __shfl(rl, g + 5);                    \
        int r6 = __shfl(rl, g + 6), r7 = __shfl(rl, g + 7);                    \
        float v0 = bf2f(xs[(size_t)r0 * 64 + lane]);                           \
        float v1 = bf2f(xs[(size_t)r1 * 64 + lane]);                           \
        float v2 = bf2f(xs[(size_t)r2 * 64 + lane]);                           \
        float v3 = bf2f(xs[(size_t)r3 * 64 + lane]);                           \
        float v4 = bf2f(xs[(size_t)r4 * 64 + lane]);                           \
        float v5 = bf2f(xs[(size_t)r5 * 64 + lane]);                           \
        float v6 = bf2f(xs[(size_t)r6 * 64 + lane]);                           \
        float v7 = bf2f(xs[(size_t)r7 * 64 + lane]);                           \
        accv += ((v0 + v1) + (v2 + v3)) + ((v4 + v5) + (v6 + v7));             \
        if (lane < 6) {                                                        \
            float u0 = bf2f(ss6[r0 * 8 + lane]), u1 = bf2f(ss6[r1 * 8 + lane]);\
            float u2 = bf2f(ss6[r2 * 8 + lane]), u3 = bf2f(ss6[r3 * 8 + lane]);\
            float u4 = bf2f(ss6[r4 * 8 + lane]), u5 = bf2f(ss6[r5 * 8 + lane]);\
            float u6 = bf2f(ss6[r6 * 8 + lane]), u7 = bf2f(ss6[r7 * 8 + lane]);\
            a6v += ((u0 + u1) + (u2 + u3)) + ((u4 + u5) + (u6 + u7));          \
        }                                                                      \
    }

// Gather-aggregate branches 1&2 + fused epilogue. Wave handles TWO nodes
// (16 independent gathers in flight). Wave-uniform group predication.
__global__ __launch_bounds__(256) void agg_fs_k(const unsigned short* __restrict__ xs,
                                                const unsigned short* __restrict__ ss6,
                                                const int* __restrict__ srcidx,
                                                const unsigned* __restrict__ rowptr,
                                                const float* __restrict__ dinv,
                                                const float* __restrict__ cw,
                                                const float* __restrict__ bfv,
                                                const float* __restrict__ Ws,
                                                const float* __restrict__ bs,
                                                const float* __restrict__ Wr,
                                                float* __restrict__ out_hf,
                                                float* __restrict__ out_hs,
                                                float* __restrict__ ps, int n) {
    int wid = threadIdx.x >> 6;
    int lane = threadIdx.x & 63;
    int iA = blockIdx.x * 8 + wid * 2;
    int iB = iA + 1;
    if (iA >= n) return;
    bool hasB = iB < n;

    unsigned eA = rowptr[iA];
    int dA = (int)(rowptr[iA + 1] - eA);
    unsigned eB = hasB ? rowptr[iB] : 0;
    int dB = hasB ? (int)(rowptr[iB + 1] - eB) : 0;

    float accA = bf2f(xs[(size_t)iA * 64 + lane]);
    float accB = hasB ? bf2f(xs[(size_t)iB * 64 + lane]) : 0.0f;
    float a6A = (lane < 6) ? bf2f(ss6[iA * 8 + lane]) : 0.0f;
    float a6B = (hasB && lane < 6) ? bf2f(ss6[iB * 8 + lane]) : 0.0f;

    int baseA = 0, baseB = 0;
    while (baseA < dA || baseB < dB) {
        int cA = min(dA - baseA, 64); cA = max(cA, 0);
        int cB = min(dB - baseB, 64); cB = max(cB, 0);
        int rlA = (lane < cA) ? srcidx[eA + baseA + lane] : 0;
        int rlB = (lane < cB) ? srcidx[eB + baseB + lane] : 0;
        int gmax = max(cA, cB);
        for (int g = 0; g + 8 <= gmax; g += 8) {
            if (g + 8 <= cA) GATHER8(rlA, g, accA, a6A);
            if (g + 8 <= cB) GATHER8(rlB, g, accB, a6B);
        }
        for (int d = cA & ~7; d < cA; d++) {
            int r = __shfl(rlA, d);
            accA += bf2f(xs[(size_t)r * 64 + lane]);
            if (lane < 6) a6A += bf2f(ss6[r * 8 + lane]);
        }
        for (int d = cB & ~7; d < cB; d++) {
            int r = __shfl(rlB, d);
            accB += bf2f(xs[(size_t)r * 64 + lane]);
            if (lane < 6) a6B += bf2f(ss6[r * 8 + lane]);
        }
        baseA += cA;
        baseB += cB;
    }

    #pragma unroll
    for (int node = 0; node < 2; node++) {
        if (node == 1 && !hasB) break;
        int i = node ? iB : iA;
        float acc = node ? accB : accA;
        float a6 = node ? a6B : a6A;
        float di = dinv[i];
        float hf = acc * di + bfv[lane];
        float hs = bs[lane];
        #pragma unroll
        for (int k = 0; k < 6; k++) hs += __shfl(a6, k) * di * Ws[k * 64 + lane];
        out_hf[(size_t)i * 64 + lane] = hf;
        out_hs[(size_t)i * 64 + lane] = hs;

        float fa = hf * cw[6];  // attr * a_a * 2
        float sa = hs * cw[7];  // struc * a_s * 2
        #pragma unroll
        for (int j = 0; j < 7; j++) {
            float v = fa * Wr[lane * 7 + j] + sa * Wr[(64 + lane) * 7 + j];
            #pragma unroll
            for (int off = 32; off; off >>= 1) v += __shfl_xor(v, off);
            if (lane == j) ps[(size_t)i * 8 + j] = v * di;
        }
        if (lane == 7) ps[(size_t)i * 8 + 7] = 0.0f;
    }
}

// Branch-3 gather: wave per node, 8 edge-slots x 8 dims; reduce via shfl_xor.
__global__ __launch_bounds__(256) void agg_y_k(const float* __restrict__ ps,
                                               const int* __restrict__ srcidx,
                                               const unsigned* __restrict__ rowptr,
                                               const float* __restrict__ dinv,
                                               const float* __restrict__ br,
                                               float* __restrict__ out_y, int n) {
    int i = blockIdx.x * 4 + (threadIdx.x >> 6);
    int lane = threadIdx.x & 63;
    if (i >= n) return;
    int es = lane >> 3, j = lane & 7;  // edge-slot, dim
    unsigned e0 = rowptr[i];
    int deg = (int)(rowptr[i + 1] - e0);
    float acc = (es == 0) ? ps[(size_t)i * 8 + j] : 0.0f;  // self-loop in slot 0
    int base = 0;
    for (; base + 16 <= deg; base += 16) {
        int ra = srcidx[e0 + base + es];
        int rb = srcidx[e0 + base + 8 + es];
        acc += ps[(size_t)ra * 8 + j] + ps[(size_t)rb * 8 + j];
    }
    for (; base < deg; base += 8) {
        int idx = base + es;
        if (idx < deg) acc += ps[(size_t)srcidx[e0 + idx] * 8 + j];
    }
    acc += __shfl_xor(acc, 8);
    acc += __shfl_xor(acc, 16);
    acc += __shfl_xor(acc, 32);
    if (j < 7) out_y[(size_t)i * 7 + j] = acc * dinv[i] + br[j];
}

extern "C" void kernel_launch(void* const* d_in, const int* in_sizes, int n_in,
                              void* d_out, int out_size, void* d_ws, size_t ws_size,
                              hipStream_t stream) {
    const float* feature   = (const float*)d_in[0];
    const float* structure = (const float*)d_in[1];
    const void*  ei        = d_in[2];
    const float* Wf  = (const float*)d_in[3];
    const float* bfv = (const float*)d_in[4];
    const float* Ws  = (const float*)d_in[5];
    const float* bs  = (const float*)d_in[6];
    const float* Wr  = (const float*)d_in[7];
    const float* br  = (const float*)d_in[8];
    const float* emb = (const float*)d_in[9];
    const float* embW = (const float*)d_in[10];
    const float* alpha_s = (const float*)d_in[11];
    const float* alpha_a = (const float*)d_in[12];

    const int N = in_sizes[0] / 512;
    const int E = in_sizes[2] / 2;
    const int NB = (N + 255) / 256;

    float* ws = (float*)d_ws;
    size_t XS     = 0;                    // N*64 ushort = N*32 floats
    size_t SS6    = XS + (size_t)N * 32;  // N*8 ushort = N*4 floats
    size_t PS     = SS6 + (size_t)N * 4;  // N*8 float
    size_t DINV   = PS + (size_t)N * 8;   // N
    size_t DEG    = DINV + N;             // N (u32)
    size_t CURSOR = DEG + N;              // N (u32)
    size_t CW     = CURSOR + N;           // 16
    size_t ROWPTR = CW + 16;              // N+1 (u32)
    size_t PART   = ROWPTR + N + 1;       // 1024 (u32)
    size_t WT     = PART + 1024;          // 32768 floats (2x 512*64 ushort)
    size_t SRC    = WT + 32768;           // E (int)

    unsigned short* xs = (unsigned short*)(ws + XS);
    unsigned short* ss6 = (unsigned short*)(ws + SS6);
    float* ps = ws + PS;
    float* dinv = ws + DINV;
    unsigned* deg = (unsigned*)(ws + DEG);
    unsigned* cursor = (unsigned*)(ws + CURSOR);
    float* cw = ws + CW;
    unsigned* rowptr = (unsigned*)(ws + ROWPTR);
    unsigned* part = (unsigned*)(ws + PART);
    unsigned short* WthG = (unsigned short*)(ws + WT);
    unsigned short* WtlG = WthG + 512 * 64;
    int* srcidx = (int*)(ws + SRC);

    // zero deg + cursor every call (ws not re-poisoned between replays)
    hipMemsetAsync(deg, 0, ((size_t)2 * N + 16) * 4, stream);
    setup_prep_k<<<129, 256, 0, stream>>>(emb, embW, alpha_s, alpha_a, cw, Wf, WthG, WtlG);
    deg_k<<<(E + 255) / 256, 256, 0, stream>>>(ei, deg, E);
    scan1_k<<<NB, 256, 0, stream>>>(deg, rowptr, part, dinv, structure, cw, ss6, N);
    scan2_k<<<1, 64, 0, stream>>>(part, NB);
    scan3_k<<<NB, 256, 0, stream>>>(rowptr, part, N, E);
    fill_k<<<(E + 255) / 256, 256, 0, stream>>>(ei, rowptr, cursor, srcidx, E);
    gemm_f_mfma<<<(N + 127) / 128, 256, 0, stream>>>(feature, WthG, WtlG, dinv, xs, N);

    float* out_hf = (float*)d_out;
    float* out_hs = out_hf + (size_t)N * 64;
    float* out_y  = out_hf + (size_t)N * 128;
    agg_fs_k<<<(N + 7) / 8, 256, 0, stream>>>(xs, ss6, srcidx, rowptr, dinv, cw,
                                              bfv, Ws, bs, Wr, out_hf, out_hs, ps, N);
    agg_y_k<<<(N + 3) / 4, 256, 0, stream>>>(ps, srcidx, rowptr, dinv, br, out_y, N);
}